// Round 3
// baseline (341.799 us; speedup 1.0000x reference)
//
#include <hip/hip_runtime.h>
#include <hip/hip_bf16.h>

typedef unsigned short ushort_t;
typedef __bf16 bf16x8 __attribute__((ext_vector_type(8)));
typedef float f32x4 __attribute__((ext_vector_type(4)));
typedef float f32x8 __attribute__((ext_vector_type(8)));

#define NTOK 1032
#define NROWS 8256       // B*N = 8*1032
#define DIMC 1024
#define QKV_ELEMS 8454144  // 8*16*1032*64 elements per tensor
#define XE 8454144         // X elements (8256*1024)
#define QWE 3145728        // qkv_w elements (3072*1024)
#define OWE 1048576        // out_w elements (1024*1024)

__device__ __forceinline__ float bf2f(ushort_t u) {
    union { unsigned int i; float f; } v; v.i = ((unsigned int)u) << 16; return v.f;
}
__device__ __forceinline__ ushort_t f2bf(float f) {
    union { float f; unsigned int i; } v; v.f = f;
    unsigned int r = v.i + 0x7fffu + ((v.i >> 16) & 1u);
    return (ushort_t)(r >> 16);
}
__device__ __forceinline__ bf16x8 cvt8(const float* p) {
    const float4 a = *(const float4*)p;
    const float4 b = *(const float4*)(p + 4);
    bf16x8 r;
    r[0] = (__bf16)a.x; r[1] = (__bf16)a.y; r[2] = (__bf16)a.z; r[3] = (__bf16)a.w;
    r[4] = (__bf16)b.x; r[5] = (__bf16)b.y; r[6] = (__bf16)b.z; r[7] = (__bf16)b.w;
    return r;
}
__device__ __forceinline__ void load_lds16(const ushort_t* g, ushort_t* l) {
    __builtin_amdgcn_global_load_lds(
        (const __attribute__((address_space(1))) unsigned int*)g,
        (__attribute__((address_space(3))) unsigned int*)l, 16, 0, 0);
}

// ---------------------------------------------------------------------------
// fp32 -> bf16 pre-conversion of X, qkv_w, out_w (RNE).
// ---------------------------------------------------------------------------
__global__ __launch_bounds__(256) void cvt_kernel(
    const float* __restrict__ X, const float* __restrict__ Wq,
    const float* __restrict__ Wo,
    ushort_t* __restrict__ Xb, ushort_t* __restrict__ Wqb,
    ushort_t* __restrict__ Wob)
{
    const long i8 = ((long)blockIdx.x * 256 + threadIdx.x) * 8;
    const float* src;
    ushort_t* dst;
    long off;
    if (i8 < XE)            { src = X;  dst = Xb;  off = i8; }
    else if (i8 < XE + QWE) { src = Wq; dst = Wqb; off = i8 - XE; }
    else                    { src = Wo; dst = Wob; off = i8 - XE - QWE; }
    *(bf16x8*)(dst + off) = cvt8(src + off);
}

// ---------------------------------------------------------------------------
// 256x256 deep-pipelined GEMM.
//   8 waves (2M x 4N), per-wave 128x64 C. BK=64, 2 LDS buffers (128 KiB).
//   Schedule as round 2 (plateau-verified; not the current lever).
//   NEW: RMSNorm + RoPE fused into the Q/K epilogue. Thread (fr,quad) holds
//   token m with features f = nf*16 + quad*4 + reg; the 64-dim head vector
//   of a token spans lanes {fr, fr+16, fr+32, fr+48} -> RMS reduce is two
//   shfl_xor (16, 32); rotate-half partner f±32 = nf^2, SAME thread.
//   rope_kernel is deleted entirely.
//   MODE 0: QKV projection (x<8 Q/K swapped+rope; x>=8 V -> Vt, dim-major).
//   MODE 1: out-projection (swap always, fp32 float4 stores), grid 4x33.
// ---------------------------------------------------------------------------
template<int MODE>
__global__ __launch_bounds__(512, 2) void gemm256_kernel(
    const ushort_t* __restrict__ A, const ushort_t* __restrict__ W,
    ushort_t* __restrict__ QKV, float* __restrict__ Out,
    const float* __restrict__ cosb, const float* __restrict__ sinb,
    const float* __restrict__ nqw, const float* __restrict__ nkw)
{
    __shared__ __align__(16) ushort_t A_lds[2 * 16384];   // 2 buf x 256 x 64
    __shared__ __align__(16) ushort_t B_lds[2 * 16384];

    const int tid  = threadIdx.x;
    const int wave = tid >> 6, lane = tid & 63;
    const int wr = wave >> 2, wc = wave & 3;        // 2 x 4 wave grid
    const int fr = lane & 15, quad = lane >> 4;
    const int m0 = blockIdx.y * 256;
    const int n0 = blockIdx.x * 256;
    const bool swap = (MODE == 1) || (blockIdx.x < 8);

    // ---- staging offsets: slot s = ld*512+tid; row=s>>3, chunk=s&7;
    //      global k-chunk = (s&7) ^ (row&7)  (involution swizzle) ----
    int aoff[4], boff[4];
    #pragma unroll
    for (int ld = 0; ld < 4; ++ld) {
        const int s   = ld * 512 + tid;
        const int row = s >> 3;
        const int kc  = ((s & 7) ^ (row & 7)) * 8;
        int ar = m0 + row; if (ar > NROWS - 1) ar = NROWS - 1;
        aoff[ld] = ar * DIMC + kc;
        boff[ld] = (n0 + row) * DIMC + kc;          // always in-bounds for W
    }

    // ---- fragment read offsets (swizzled chunk, constant per lane) ----
    const int ck0 = (quad ^ (fr & 7)) * 8;          // k-sub 0 (k 0..31)
    const int ck1 = ((quad + 4) ^ (fr & 7)) * 8;    // k-sub 1 (k 32..63)
    const int abase = (wr * 128 + fr) * 64;
    const int bbase = (wc * 64 + fr) * 64;

    f32x4 acc[8][4] = {};

#define SA(ld, t, c) load_lds16(A + aoff[ld] + (t) * 64, \
                                &A_lds[(c) * 16384 + ((ld) * 512 + tid) * 8])
#define SB(ld, t, c) load_lds16(W + boff[ld] + (t) * 64, \
                                &B_lds[(c) * 16384 + ((ld) * 512 + tid) * 8])
#define WAIT_LGKM0 asm volatile("s_waitcnt lgkmcnt(0)" ::: "memory")
#define WAIT_VM6   asm volatile("s_waitcnt vmcnt(6)"  ::: "memory")
#define WAIT_VM0   asm volatile("s_waitcnt vmcnt(0)"  ::: "memory")

#define READ_AF(p) \
    af[0][0] = *(const bf16x8*)&A_lds[cb + abase + ((p) * 2 + 0) * 1024 + ck0]; \
    af[0][1] = *(const bf16x8*)&A_lds[cb + abase + ((p) * 2 + 0) * 1024 + ck1]; \
    af[1][0] = *(const bf16x8*)&A_lds[cb + abase + ((p) * 2 + 1) * 1024 + ck0]; \
    af[1][1] = *(const bf16x8*)&A_lds[cb + abase + ((p) * 2 + 1) * 1024 + ck1];

#define MFMA_PHASE(p) \
    __builtin_amdgcn_s_setprio(1); \
    if (swap) { \
        _Pragma("unroll") \
        for (int mfi = 0; mfi < 2; ++mfi) \
            _Pragma("unroll") \
            for (int nf = 0; nf < 4; ++nf) { \
                acc[(p) * 2 + mfi][nf] = __builtin_amdgcn_mfma_f32_16x16x32_bf16( \
                    bfrag[nf][0], af[mfi][0], acc[(p) * 2 + mfi][nf], 0, 0, 0); \
                acc[(p) * 2 + mfi][nf] = __builtin_amdgcn_mfma_f32_16x16x32_bf16( \
                    bfrag[nf][1], af[mfi][1], acc[(p) * 2 + mfi][nf], 0, 0, 0); \
            } \
    } else { \
        _Pragma("unroll") \
        for (int mfi = 0; mfi < 2; ++mfi) \
            _Pragma("unroll") \
            for (int nf = 0; nf < 4; ++nf) { \
                acc[(p) * 2 + mfi][nf] = __builtin_amdgcn_mfma_f32_16x16x32_bf16( \
                    af[mfi][0], bfrag[nf][0], acc[(p) * 2 + mfi][nf], 0, 0, 0); \
                acc[(p) * 2 + mfi][nf] = __builtin_amdgcn_mfma_f32_16x16x32_bf16( \
                    af[mfi][1], bfrag[nf][1], acc[(p) * 2 + mfi][nf], 0, 0, 0); \
            } \
    } \
    __builtin_amdgcn_s_setprio(0);

    // ---- prologue: tile0 complete (8), tile1 B+A-lo (6) ----
    SB(0, 0, 0); SB(1, 0, 0); SB(2, 0, 0); SB(3, 0, 0);
    SA(0, 0, 0); SA(1, 0, 0); SA(2, 0, 0); SA(3, 0, 0);
    SB(0, 1, 1); SB(1, 1, 1); SB(2, 1, 1); SB(3, 1, 1);
    SA(0, 1, 1); SA(2, 1, 1);               // ld0,ld2 = rows 0-63 & 128-191
    WAIT_VM6;                               // tile0 done; tile1's 6 in flight
    __builtin_amdgcn_s_barrier();

    for (int t = 0; t < 16; ++t) {
        const int c = t & 1, o = c ^ 1;
        const int cb = c * 16384;
        bf16x8 bfrag[4][2];
        bf16x8 af[2][2];

        // ---- phase 0: B frags + A quadrant 0 ----
        #pragma unroll
        for (int nf = 0; nf < 4; ++nf) {
            bfrag[nf][0] = *(const bf16x8*)&B_lds[cb + bbase + nf * 1024 + ck0];
            bfrag[nf][1] = *(const bf16x8*)&B_lds[cb + bbase + nf * 1024 + ck1];
        }
        READ_AF(0);
        if (t < 15) { SA(1, t + 1, o); SA(3, t + 1, o); }
        __builtin_amdgcn_s_barrier();
        WAIT_LGKM0; __builtin_amdgcn_sched_barrier(0);
        MFMA_PHASE(0);
        __builtin_amdgcn_s_barrier();       // T0: B(cur) now dead

        // ---- phase 1 ----
        READ_AF(1);
        if (t < 14) { SB(0, t + 2, c); SB(1, t + 2, c);
                      SB(2, t + 2, c); SB(3, t + 2, c); }
        __builtin_amdgcn_s_barrier();
        WAIT_LGKM0; __builtin_amdgcn_sched_barrier(0);
        MFMA_PHASE(1);
        __builtin_amdgcn_s_barrier();       // T1: A-lo(cur) now dead

        // ---- phase 2 ----
        READ_AF(2);
        if (t < 14) { SA(0, t + 2, c); SA(2, t + 2, c); }
        __builtin_amdgcn_s_barrier();
        WAIT_LGKM0; __builtin_amdgcn_sched_barrier(0);
        MFMA_PHASE(2);
        // no trailing barrier: nothing stages into regions read in p2/p3
        // until after the boundary barrier.

        // ---- phase 3 ----
        READ_AF(3);
        __builtin_amdgcn_s_barrier();
        WAIT_LGKM0; __builtin_amdgcn_sched_barrier(0);
        MFMA_PHASE(3);

        // ---- tile boundary: next buffer complete, 6 loads stay in flight ----
        if (t < 14)       { WAIT_VM6; __builtin_amdgcn_s_barrier(); }
        else if (t == 14) { WAIT_VM0; __builtin_amdgcn_s_barrier(); }
    }

    // ---- epilogue ----
    const int rb = quad * 4;
    if (MODE == 1) {
        // out proj: D[col = token m][regs = feature] -> float4 stores
        #pragma unroll
        for (int mf = 0; mf < 8; ++mf) {
            const int m = m0 + wr * 128 + mf * 16 + fr;
            if (m < NROWS) {
                #pragma unroll
                for (int nf = 0; nf < 4; ++nf) {
                    const int o_ = n0 + wc * 64 + nf * 16 + rb;
                    float4 pk;
                    pk.x = acc[mf][nf][0];
                    pk.y = acc[mf][nf][1];
                    pk.z = acc[mf][nf][2];
                    pk.w = acc[mf][nf][3];
                    *(float4*)(Out + (long)m * DIMC + o_) = pk;
                }
            }
        }
    } else if (swap) {
        // Q/K: D[col = token m][regs = feature]; wave-col (wc) = one head.
        // Fused RMSNorm + RoPE (token's 64 dims live in lanes fr+16*quad).
        const int part   = n0 >> 10;                 // 0 = Q, 1 = K
        const int hgbase = ((n0 & 1023) + wc * 64) >> 6;
        const float* wtab = (part == 0) ? nqw : nkw;
        float4 w4[4];
        #pragma unroll
        for (int nf = 0; nf < 4; ++nf)
            w4[nf] = *(const float4*)(wtab + nf * 16 + rb);
        #pragma unroll
        for (int mf = 0; mf < 8; ++mf) {
            const int m = m0 + wr * 128 + mf * 16 + fr;
            if (m < NROWS) {
                const int bb = m / NTOK, n = m - bb * NTOK;
                // per-thread partial sum of squares over 16 features
                float x[4][4];
                float ss = 0.f;
                #pragma unroll
                for (int nf = 0; nf < 4; ++nf)
                    #pragma unroll
                    for (int r = 0; r < 4; ++r) {
                        x[nf][r] = acc[mf][nf][r];
                        ss += x[nf][r] * x[nf][r];
                    }
                // cross-quad reduce: lanes fr, fr+16, fr+32, fr+48 share token
                ss += __shfl_xor(ss, 16, 64);
                ss += __shfl_xor(ss, 32, 64);
                const float rms = rsqrtf(ss * (1.0f / 64.0f) + 1e-6f);
                const float* cosp = cosb + n * 64 + rb;
                const float* sinp = sinb + n * 64 + rb;
                ushort_t* outb = QKV + (long)part * QKV_ELEMS +
                    ((long)(bb * 16 + hgbase) * NTOK + n) * 64 + rb;
                #pragma unroll
                for (int nf = 0; nf < 4; ++nf) {
                    const float4 c4 = *(const float4*)(cosp + nf * 16);
                    const float4 s4 = *(const float4*)(sinp + nf * 16);
                    const int pn = nf ^ 2;           // rotate-half partner
                    const float sgn = (nf < 2) ? -1.f : 1.f;
                    ushort4 pk;
                    {
                        const float xn  = x[nf][0] * rms * w4[nf].x;
                        const float rot = sgn * x[pn][0] * rms * w4[pn].x;
                        pk.x = f2bf(xn * c4.x + rot * s4.x);
                    }
                    {
                        const float xn  = x[nf][1] * rms * w4[nf].y;
                        const float rot = sgn * x[pn][1] * rms * w4[pn].y;
                        pk.y = f2bf(xn * c4.y + rot * s4.y);
                    }
                    {
                        const float xn  = x[nf][2] * rms * w4[nf].z;
                        const float rot = sgn * x[pn][2] * rms * w4[pn].z;
                        pk.z = f2bf(xn * c4.z + rot * s4.z);
                    }
                    {
                        const float xn  = x[nf][3] * rms * w4[nf].w;
                        const float rot = sgn * x[pn][3] * rms * w4[pn].w;
                        pk.w = f2bf(xn * c4.w + rot * s4.w);
                    }
                    *(ushort4*)(outb + nf * 16) = pk;
                }
            }
        }
    } else {
        // V: D[col = feature][regs = token] -> Vt[bh][d][n] (dim-major)
        const int hg = ((n0 & 1023) + wc * 64) >> 6;
        #pragma unroll
        for (int nf = 0; nf < 4; ++nf) {
            const int d = nf * 16 + fr;
            #pragma unroll
            for (int mf = 0; mf < 8; ++mf) {
                const int mb = m0 + wr * 128 + mf * 16 + rb;
                if (mb < NROWS) {
                    const int bb = mb / NTOK, n = mb - bb * NTOK;
                    ushort4 pk;
                    pk.x = f2bf(acc[mf][nf][0]);
                    pk.y = f2bf(acc[mf][nf][1]);
                    pk.z = f2bf(acc[mf][nf][2]);
                    pk.w = f2bf(acc[mf][nf][3]);
                    *(ushort4*)(QKV + 2L * QKV_ELEMS +
                        ((long)((bb * 16 + hg) * 64 + d)) * NTOK + n) = pk;
                }
            }
        }
    }
#undef SA
#undef SB
#undef WAIT_LGKM0
#undef WAIT_VM6
#undef WAIT_VM0
#undef READ_AF
#undef MFMA_PHASE
}

// ---------------------------------------------------------------------------
// Merged attention (unchanged).
// ---------------------------------------------------------------------------
__global__ __launch_bounds__(256) void attn_kernel(
    const ushort_t* __restrict__ Qb, const ushort_t* __restrict__ Kb,
    const ushort_t* __restrict__ Vt, ushort_t* __restrict__ AO)
{
    __shared__ __align__(16) ushort_t KP_s[256 * 72];

    const int tid = threadIdx.x;
    const int wave = tid >> 6, lane = tid & 63;
    const int m_ = lane & 15, quad = lane >> 4;
    const int nb = wave * 64;
    const int d0 = wave * 16;

    bf16x8 ones;
    #pragma unroll
    for (int e = 0; e < 8; ++e) ones[e] = (__bf16)1.0f;

    if (blockIdx.x >= 128) {
        const int blk = blockIdx.x - 128;
        const int bh = blk & 127, qr = blk >> 7;
        const int b = bh >> 4, h = bh & 15;

        int r0 = qr - 3; if (r0 < 0) r0 = 0;
        int r1 = qr + 3; if (r1 > 31) r1 = 31;
        const int limit = 8 + (r1 - r0 + 1) * 32;

        const ushort_t* Qg  = Qb + ((long)bh * NTOK + 8 + qr * 32) * 64;
        const ushort_t* Kg  = Kb + (long)bh * NTOK * 64;
        const ushort_t* Vtg = Vt + (long)bh * 64 * NTOK;

        bf16x8 af[2][2];
        #pragma unroll
        for (int mt = 0; mt < 2; ++mt)
            #pragma unroll
            for (int ks = 0; ks < 2; ++ks)
                af[mt][ks] = *(const bf16x8*)(Qg + (mt * 16 + m_) * 64 + ks * 32 + quad * 8);

        bf16x8 bv[8];
        #pragma unroll
        for (int ks = 0; ks < 8; ++ks) {
            const int slot0 = ks * 32 + quad * 8;
            int tok0;
            if (slot0 >= limit) tok0 = 0;
            else if (slot0 < 8) tok0 = slot0;
            else tok0 = 8 + r0 * 32 + (slot0 - 8);
            bv[ks] = *(const bf16x8*)(Vtg + (long)(d0 + m_) * NTOK + tok0);
        }

        for (int c = tid; c < limit * 8; c += 256) {
            const int slot = c >> 3, c8 = (c & 7) * 8;
            const int tok = slot + (slot >= 8 ? r0 * 32 : 0);
            *(bf16x8*)&KP_s[slot * 72 + c8] = *(const bf16x8*)(Kg + (long)tok * 64 + c8);
        }
        __syncthreads();

        bf16x8 bfr[4][2];
        #pragma unroll
        for (int nt = 0; nt < 4; ++nt)
            #pragma unroll
            for (int ks = 0; ks < 2; ++ks)
                bfr[nt][ks] = *(const bf16x8*)&KP_s[(nb + nt * 16 + m_) * 72 + ks * 32 + quad * 8];

        f32x4 sacc[2][4] = {};
        #pragma unroll
        for (int mt = 0; mt < 2; ++mt)
            #pragma unroll
            for (int nt = 0; nt < 4; ++nt) {
                sacc[mt][nt] = __builtin_amdgcn_mfma_f32_16x16x32_bf16(
                    af[mt][0], bfr[nt][0], sacc[mt][nt], 0, 0, 0);
                sacc[mt][nt] = __builtin_amdgcn_mfma_f32_16x16x32_bf16(
                    af[mt][1], bfr[nt][1], sacc[mt][nt], 0, 0, 0);
            }
        __syncthreads();

        #pragma unroll
        for (int mt = 0; mt < 2; ++mt)
            #pragma unroll
            for (int nt = 0; nt < 4; ++nt) {
                const int slot = nb + nt * 16 + m_;
                const int kc = (slot - 8) & 31;
                #pragma unroll
                for (int reg = 0; reg < 4; ++reg) {
                    const int qm = mt * 16 + quad * 4 + reg;
                    const bool val = (slot < 8) ||
                        ((slot < limit) && ((unsigned)(kc - qm + 3) <= 6u));
                    const float p = val ? __expf(sacc[mt][nt][reg] * 0.125f) : 0.f;
                    KP_s[qm * 280 + slot] = f2bf(p);
                }
            }
        __syncthreads();

        f32x4 oacc[2] = {}, lacc[2] = {};
        #pragma unroll
        for (int ks = 0; ks < 8; ++ks) {
            #pragma unroll
            for (int mt = 0; mt < 2; ++mt) {
                const bf16x8 ap = *(const bf16x8*)&KP_s[(mt * 16 + m_) * 280 + ks * 32 + quad * 8];
                oacc[mt] = __builtin_amdgcn_mfma_f32_16x16x32_bf16(ap, bv[ks], oacc[mt], 0, 0, 0);
                lacc[mt] = __builtin_amdgcn_mfma_f32_16x16x32_bf16(ap, ones,   lacc[mt], 0, 0, 0);
            }
        }
        #pragma unroll
        for (int mt = 0; mt < 2; ++mt)
            #pragma unroll
            for (int reg = 0; reg < 4; ++reg) {
                const int qm = mt * 16 + quad * 4 + reg;
                const int tok = 8 + qr * 32 + qm;
                AO[((long)(b * NTOK + tok)) * DIMC + h * 64 + d0 + m_] =
                    f2bf(oacc[mt][reg] / lacc[mt][reg]);
            }
    } else {
        const int bh = blockIdx.x;
        const int b = bh >> 4, h = bh & 15;
        const ushort_t* Kg  = Kb + (long)bh * NTOK * 64;
        const ushort_t* Vtg = Vt + (long)bh * 64 * NTOK;

        bf16x8 afs[2];
        if (m_ < 8) {
            #pragma unroll
            for (int ks = 0; ks < 2; ++ks)
                afs[ks] = *(const bf16x8*)(Qb + ((long)bh * NTOK + m_) * 64 + ks * 32 + quad * 8);
        } else {
            #pragma unroll
            for (int ks = 0; ks < 2; ++ks)
                #pragma unroll
                for (int e = 0; e < 8; ++e) afs[ks][e] = (__bf16)0.f;
        }

        f32x4 oacc = {}, lacc = {};
        for (int ch = 0; ch < 5; ++ch) {
            const int tok0 = ch * 256;
            const int limit = (NTOK - tok0 < 256) ? (NTOK - tok0) : 256;

            bf16x8 bv[8];
            #pragma unroll
            for (int ks = 0; ks < 8; ++ks) {
                const int slot0 = ks * 32 + quad * 8;
                const int tok = tok0 + ((slot0 < limit) ? slot0 : 0);
                bv[ks] = *(const bf16x8*)(Vtg + (long)(d0 + m_) * NTOK + tok);
            }

            __syncthreads();
            for (int c = tid; c < limit * 8; c += 256) {
                const int slot = c >> 3, c8 = (c & 7) * 8;
                *(bf16x8*)&KP_s[slot * 72 + c8] =
                    *(const bf16x8*)(Kg + (long)(tok0 + slot) * 64 + c8);
            }
            __syncthreads();

            bf16x8 bfr[4][2];
            #pragma unroll
            for (int nt = 0; nt < 4; ++nt)
                #pragma unroll
                for (int ks = 0; ks < 2; ++ks)
                    bfr[nt][ks] = *(const bf16x8*)&KP_s[(nb + nt * 16 + m_) * 72 + ks * 32 + quad * 8];
            f32x4 sacc[4] = {};
            #pragma unroll
            for (int nt = 0; nt < 4; ++nt) {
                sacc[nt] = __builtin_amdgcn_mfma_f32_16x16x32_bf16(afs[0], bfr[nt][0], sacc[nt], 0, 0, 0);
                sacc[nt] = __builtin_amdgcn_mfma_f32_16x16x32_bf16(afs[1], bfr[nt][1], sacc[nt], 0, 0, 0);
            }
            __syncthreads();

            #pragma unroll
            for (int nt = 0; nt < 4; ++nt) {
                const int slot = nb + nt * 16 + m_;
                const bool val = (slot < limit);
                #pragma unroll
                for (int reg = 0; reg < 4; ++reg) {
                    const int qm = quad * 4 + reg;
                    const float p = val ? __expf(sacc[nt][reg] * 0.125f) : 0.f;
                    KP_s[qm * 280 + slot] = f2bf(p);
                }
            }
            __syncthreads();

            #pragma unroll
            for (int ks = 0; ks < 8; ++ks) {
                const bf16x8 ap = *(const bf16x8*)&KP_s[m_ * 280 + ks * 32 + quad * 8];
                oacc = __builtin_amdgcn_mfma_f32_16x16x32_bf16(ap, bv[ks], oacc, 0, 0, 0);
                lacc = __builtin_amdgcn_mfma_f32_16x16x32_bf16(ap, ones,   lacc, 0, 0, 0);
            }
        }

        #pragma unroll
        for (int reg = 0; reg < 4; ++reg) {
            const int qm = quad * 4 + reg;
            if (qm < 8) {
                AO[((long)(b * NTOK + qm)) * DIMC + h * 64 + d0 + m_] =
                    f2bf(oacc[reg] / lacc[reg]);
            }
        }
    }
}

extern "C" void kernel_launch(void* const* d_in, const int* in_sizes, int n_in,
                              void* d_out, int out_size, void* d_ws, size_t ws_size,
                              hipStream_t stream) {
    const float* X    = (const float*)d_in[0];
    const float* fc   = (const float*)d_in[1];
    const float* fs   = (const float*)d_in[2];
    const float* qkvw = (const float*)d_in[3];
    const float* outw = (const float*)d_in[4];
    const float* nqw  = (const float*)d_in[5];
    const float* nkw  = (const float*)d_in[6];

    ushort_t* Qb  = (ushort_t*)d_ws;
    ushort_t* Kb  = Qb + QKV_ELEMS;
    ushort_t* Vt  = Kb + QKV_ELEMS;
    ushort_t* AO  = Vt + QKV_ELEMS;
    ushort_t* Xb  = AO + QKV_ELEMS;
    ushort_t* Wqb = Xb + XE;
    ushort_t* Wob = Wqb + QWE;
    float* Out = (float*)d_out;

    cvt_kernel<<<6176, 256, 0, stream>>>(X, qkvw, outw, Xb, Wqb, Wob);
    gemm256_kernel<0><<<dim3(12, 33), 512, 0, stream>>>(Xb, Wqb, Qb, nullptr,
                                                        fc, fs, nqw, nkw);
    attn_kernel<<<4224, 256, 0, stream>>>(Qb, Kb, Vt, AO);
    gemm256_kernel<1><<<dim3(4, 33), 512, 0, stream>>>(AO, Wob, nullptr, Out,
                                                       fc, fs, nqw, nkw);
}

// Round 4
// 336.000 us; speedup vs baseline: 1.0173x; 1.0173x over previous
//
#include <hip/hip_runtime.h>
#include <hip/hip_bf16.h>

typedef unsigned short ushort_t;
typedef __bf16 bf16x8 __attribute__((ext_vector_type(8)));
typedef float f32x4 __attribute__((ext_vector_type(4)));
typedef float f32x8 __attribute__((ext_vector_type(8)));

#define NTOK 1032
#define NROWS 8256       // B*N = 8*1032
#define DIMC 1024
#define QKV_ELEMS 8454144  // 8*16*1032*64 elements per tensor
#define XE 8454144         // X elements (8256*1024)
#define QWE 3145728        // qkv_w elements (3072*1024)
#define OWE 1048576        // out_w elements (1024*1024)

__device__ __forceinline__ float bf2f(ushort_t u) {
    union { unsigned int i; float f; } v; v.i = ((unsigned int)u) << 16; return v.f;
}
__device__ __forceinline__ ushort_t f2bf(float f) {
    union { float f; unsigned int i; } v; v.f = f;
    unsigned int r = v.i + 0x7fffu + ((v.i >> 16) & 1u);
    return (ushort_t)(r >> 16);
}
__device__ __forceinline__ bf16x8 cvt8(const float* p) {
    const float4 a = *(const float4*)p;
    const float4 b = *(const float4*)(p + 4);
    bf16x8 r;
    r[0] = (__bf16)a.x; r[1] = (__bf16)a.y; r[2] = (__bf16)a.z; r[3] = (__bf16)a.w;
    r[4] = (__bf16)b.x; r[5] = (__bf16)b.y; r[6] = (__bf16)b.z; r[7] = (__bf16)b.w;
    return r;
}
__device__ __forceinline__ void load_lds16(const ushort_t* g, ushort_t* l) {
    __builtin_amdgcn_global_load_lds(
        (const __attribute__((address_space(1))) unsigned int*)g,
        (__attribute__((address_space(3))) unsigned int*)l, 16, 0, 0);
}

// ---------------------------------------------------------------------------
// fp32 -> bf16 pre-conversion of X, qkv_w, out_w (RNE).
// ---------------------------------------------------------------------------
__global__ __launch_bounds__(256) void cvt_kernel(
    const float* __restrict__ X, const float* __restrict__ Wq,
    const float* __restrict__ Wo,
    ushort_t* __restrict__ Xb, ushort_t* __restrict__ Wqb,
    ushort_t* __restrict__ Wob)
{
    const long i8 = ((long)blockIdx.x * 256 + threadIdx.x) * 8;
    const float* src;
    ushort_t* dst;
    long off;
    if (i8 < XE)            { src = X;  dst = Xb;  off = i8; }
    else if (i8 < XE + QWE) { src = Wq; dst = Wqb; off = i8 - XE; }
    else                    { src = Wo; dst = Wob; off = i8 - XE - QWE; }
    *(bf16x8*)(dst + off) = cvt8(src + off);
}

// ---------------------------------------------------------------------------
// 256x256 deep-pipelined GEMM.
//   8 waves (2M x 4N), per-wave 128x64 C. BK=64, 2 LDS buffers.
//   Fused RMSNorm + RoPE in the Q/K epilogue (round 3), but with the cos/sin
//   tables STAGED INTO LDS coalesced (round 3's per-thread scattered global
//   float4 table loads caused L2 thrash: FETCH +18MB, WRITE +31MB write
//   amplification, MODE0 91->163us). GEMM LDS buffers are dead after the
//   K-loop -> overlay. Layout: token row r (0..255), feature f: pairs
//   (cos,sin) interleaved at T[r*132 + f*2]; stride 132 % 32 = 4 -> <=2-way
//   bank conflict. 132KB SMEM (MODE 0), still 1 block/CU.
//   MODE 0: QKV projection (x<8 Q/K swapped + fused norm/rope; x>=8 V->Vt).
//   MODE 1: out-projection (swap always, fp32 float4 stores), grid 4x33.
// ---------------------------------------------------------------------------
template<int MODE>
__global__ __launch_bounds__(512, 2) void gemm256_kernel(
    const ushort_t* __restrict__ A, const ushort_t* __restrict__ W,
    ushort_t* __restrict__ QKV, float* __restrict__ Out,
    const float* __restrict__ cosb, const float* __restrict__ sinb,
    const float* __restrict__ nqw, const float* __restrict__ nkw)
{
    constexpr int SMEM_BYTES = (MODE == 0) ? 135168 : 131072;
    __shared__ __align__(16) unsigned char SMEM[SMEM_BYTES];
    ushort_t* A_lds = (ushort_t*)SMEM;              // 2 buf x 256 x 64 (64KB)
    ushort_t* B_lds = (ushort_t*)(SMEM + 65536);    // 64KB

    const int tid  = threadIdx.x;
    const int wave = tid >> 6, lane = tid & 63;
    const int wr = wave >> 2, wc = wave & 3;        // 2 x 4 wave grid
    const int fr = lane & 15, quad = lane >> 4;
    const int m0 = blockIdx.y * 256;
    const int n0 = blockIdx.x * 256;
    const bool swap = (MODE == 1) || (blockIdx.x < 8);

    // ---- staging offsets: slot s = ld*512+tid; row=s>>3, chunk=s&7;
    //      global k-chunk = (s&7) ^ (row&7)  (involution swizzle) ----
    int aoff[4], boff[4];
    #pragma unroll
    for (int ld = 0; ld < 4; ++ld) {
        const int s   = ld * 512 + tid;
        const int row = s >> 3;
        const int kc  = ((s & 7) ^ (row & 7)) * 8;
        int ar = m0 + row; if (ar > NROWS - 1) ar = NROWS - 1;
        aoff[ld] = ar * DIMC + kc;
        boff[ld] = (n0 + row) * DIMC + kc;          // always in-bounds for W
    }

    // ---- fragment read offsets (swizzled chunk, constant per lane) ----
    const int ck0 = (quad ^ (fr & 7)) * 8;          // k-sub 0 (k 0..31)
    const int ck1 = ((quad + 4) ^ (fr & 7)) * 8;    // k-sub 1 (k 32..63)
    const int abase = (wr * 128 + fr) * 64;
    const int bbase = (wc * 64 + fr) * 64;

    f32x4 acc[8][4] = {};

#define SA(ld, t, c) load_lds16(A + aoff[ld] + (t) * 64, \
                                &A_lds[(c) * 16384 + ((ld) * 512 + tid) * 8])
#define SB(ld, t, c) load_lds16(W + boff[ld] + (t) * 64, \
                                &B_lds[(c) * 16384 + ((ld) * 512 + tid) * 8])
#define WAIT_LGKM0 asm volatile("s_waitcnt lgkmcnt(0)" ::: "memory")
#define WAIT_VM6   asm volatile("s_waitcnt vmcnt(6)"  ::: "memory")
#define WAIT_VM0   asm volatile("s_waitcnt vmcnt(0)"  ::: "memory")

#define READ_AF(p) \
    af[0][0] = *(const bf16x8*)&A_lds[cb + abase + ((p) * 2 + 0) * 1024 + ck0]; \
    af[0][1] = *(const bf16x8*)&A_lds[cb + abase + ((p) * 2 + 0) * 1024 + ck1]; \
    af[1][0] = *(const bf16x8*)&A_lds[cb + abase + ((p) * 2 + 1) * 1024 + ck0]; \
    af[1][1] = *(const bf16x8*)&A_lds[cb + abase + ((p) * 2 + 1) * 1024 + ck1];

#define MFMA_PHASE(p) \
    __builtin_amdgcn_s_setprio(1); \
    if (swap) { \
        _Pragma("unroll") \
        for (int mfi = 0; mfi < 2; ++mfi) \
            _Pragma("unroll") \
            for (int nf = 0; nf < 4; ++nf) { \
                acc[(p) * 2 + mfi][nf] = __builtin_amdgcn_mfma_f32_16x16x32_bf16( \
                    bfrag[nf][0], af[mfi][0], acc[(p) * 2 + mfi][nf], 0, 0, 0); \
                acc[(p) * 2 + mfi][nf] = __builtin_amdgcn_mfma_f32_16x16x32_bf16( \
                    bfrag[nf][1], af[mfi][1], acc[(p) * 2 + mfi][nf], 0, 0, 0); \
            } \
    } else { \
        _Pragma("unroll") \
        for (int mfi = 0; mfi < 2; ++mfi) \
            _Pragma("unroll") \
            for (int nf = 0; nf < 4; ++nf) { \
                acc[(p) * 2 + mfi][nf] = __builtin_amdgcn_mfma_f32_16x16x32_bf16( \
                    af[mfi][0], bfrag[nf][0], acc[(p) * 2 + mfi][nf], 0, 0, 0); \
                acc[(p) * 2 + mfi][nf] = __builtin_amdgcn_mfma_f32_16x16x32_bf16( \
                    af[mfi][1], bfrag[nf][1], acc[(p) * 2 + mfi][nf], 0, 0, 0); \
            } \
    } \
    __builtin_amdgcn_s_setprio(0);

    // ---- prologue: tile0 complete (8), tile1 B+A-lo (6) ----
    SB(0, 0, 0); SB(1, 0, 0); SB(2, 0, 0); SB(3, 0, 0);
    SA(0, 0, 0); SA(1, 0, 0); SA(2, 0, 0); SA(3, 0, 0);
    SB(0, 1, 1); SB(1, 1, 1); SB(2, 1, 1); SB(3, 1, 1);
    SA(0, 1, 1); SA(2, 1, 1);               // ld0,ld2 = rows 0-63 & 128-191
    WAIT_VM6;                               // tile0 done; tile1's 6 in flight
    __builtin_amdgcn_s_barrier();

    for (int t = 0; t < 16; ++t) {
        const int c = t & 1, o = c ^ 1;
        const int cb = c * 16384;
        bf16x8 bfrag[4][2];
        bf16x8 af[2][2];

        // ---- phase 0: B frags + A quadrant 0 ----
        #pragma unroll
        for (int nf = 0; nf < 4; ++nf) {
            bfrag[nf][0] = *(const bf16x8*)&B_lds[cb + bbase + nf * 1024 + ck0];
            bfrag[nf][1] = *(const bf16x8*)&B_lds[cb + bbase + nf * 1024 + ck1];
        }
        READ_AF(0);
        if (t < 15) { SA(1, t + 1, o); SA(3, t + 1, o); }
        __builtin_amdgcn_s_barrier();
        WAIT_LGKM0; __builtin_amdgcn_sched_barrier(0);
        MFMA_PHASE(0);
        __builtin_amdgcn_s_barrier();       // T0: B(cur) now dead

        // ---- phase 1 ----
        READ_AF(1);
        if (t < 14) { SB(0, t + 2, c); SB(1, t + 2, c);
                      SB(2, t + 2, c); SB(3, t + 2, c); }
        __builtin_amdgcn_s_barrier();
        WAIT_LGKM0; __builtin_amdgcn_sched_barrier(0);
        MFMA_PHASE(1);
        __builtin_amdgcn_s_barrier();       // T1: A-lo(cur) now dead

        // ---- phase 2 ----
        READ_AF(2);
        if (t < 14) { SA(0, t + 2, c); SA(2, t + 2, c); }
        __builtin_amdgcn_s_barrier();
        WAIT_LGKM0; __builtin_amdgcn_sched_barrier(0);
        MFMA_PHASE(2);
        // no trailing barrier: nothing stages into regions read in p2/p3
        // until after the boundary barrier.

        // ---- phase 3 ----
        READ_AF(3);
        __builtin_amdgcn_s_barrier();
        WAIT_LGKM0; __builtin_amdgcn_sched_barrier(0);
        MFMA_PHASE(3);

        // ---- tile boundary: next buffer complete, 6 loads stay in flight ----
        if (t < 14)       { WAIT_VM6; __builtin_amdgcn_s_barrier(); }
        else if (t == 14) { WAIT_VM0; __builtin_amdgcn_s_barrier(); }
    }

    // ---- epilogue ----
    const int rb = quad * 4;
    if (MODE == 1) {
        // out proj: D[col = token m][regs = feature] -> float4 stores
        #pragma unroll
        for (int mf = 0; mf < 8; ++mf) {
            const int m = m0 + wr * 128 + mf * 16 + fr;
            if (m < NROWS) {
                #pragma unroll
                for (int nf = 0; nf < 4; ++nf) {
                    const int o_ = n0 + wc * 64 + nf * 16 + rb;
                    float4 pk;
                    pk.x = acc[mf][nf][0];
                    pk.y = acc[mf][nf][1];
                    pk.z = acc[mf][nf][2];
                    pk.w = acc[mf][nf][3];
                    *(float4*)(Out + (long)m * DIMC + o_) = pk;
                }
            }
        }
    } else if (swap) {
        // Q/K: D[col = token m][regs = feature]; wave-col (wc) = one head.
        // Fused RMSNorm + RoPE; cos/sin staged to LDS coalesced first.
        const int part   = n0 >> 10;                 // 0 = Q, 1 = K
        const int hgbase = ((n0 & 1023) + wc * 64) >> 6;
        const float* wtab = (part == 0) ? nqw : nkw;
        float4 w4[4];
        #pragma unroll
        for (int nf = 0; nf < 4; ++nf)
            w4[nf] = *(const float4*)(wtab + nf * 16 + rb);

        // ---- stage cos/sin slice (256 tokens x 64 feat, (c,s) pairs) ----
        float* T = (float*)SMEM;
        __syncthreads();                     // all waves done with GEMM LDS
        for (int e = tid; e < 256 * 16; e += 512) {
            const int row = e >> 4, seg = e & 15;
            const int mm  = m0 + row;
            const int bb2 = mm / NTOK;
            const int n2  = mm - bb2 * NTOK;  // <= 1031 even for dead rows
            const float4 c4 = *(const float4*)(cosb + n2 * 64 + seg * 4);
            const float4 s4 = *(const float4*)(sinb + n2 * 64 + seg * 4);
            float* dst = T + row * 132 + seg * 8;
            ((float2*)dst)[0] = make_float2(c4.x, s4.x);
            ((float2*)dst)[1] = make_float2(c4.y, s4.y);
            ((float2*)dst)[2] = make_float2(c4.z, s4.z);
            ((float2*)dst)[3] = make_float2(c4.w, s4.w);
        }
        __syncthreads();

        #pragma unroll
        for (int mf = 0; mf < 8; ++mf) {
            const int rr = wr * 128 + mf * 16 + fr;   // token row in block
            const int m  = m0 + rr;
            if (m < NROWS) {
                const int bb = m / NTOK, n = m - bb * NTOK;
                // per-thread partial sum of squares over 16 features
                float x[4][4];
                float ss = 0.f;
                #pragma unroll
                for (int nf = 0; nf < 4; ++nf)
                    #pragma unroll
                    for (int r = 0; r < 4; ++r) {
                        x[nf][r] = acc[mf][nf][r];
                        ss += x[nf][r] * x[nf][r];
                    }
                // cross-quad reduce: lanes fr, fr+16, fr+32, fr+48 share token
                ss += __shfl_xor(ss, 16, 64);
                ss += __shfl_xor(ss, 32, 64);
                const float rms = rsqrtf(ss * (1.0f / 64.0f) + 1e-6f);
                const float* trow = T + rr * 132;
                ushort_t* outb = QKV + (long)part * QKV_ELEMS +
                    ((long)(bb * 16 + hgbase) * NTOK + n) * 64 + rb;
                #pragma unroll
                for (int nf = 0; nf < 4; ++nf) {
                    const float4 q0 = *(const float4*)(trow + (nf * 16 + rb) * 2);
                    const float4 q1 = *(const float4*)(trow + (nf * 16 + rb) * 2 + 4);
                    const float cc[4] = { q0.x, q0.z, q1.x, q1.z };
                    const float sn[4] = { q0.y, q0.w, q1.y, q1.w };
                    const int pn = nf ^ 2;           // rotate-half partner
                    const float sgn = (nf < 2) ? -1.f : 1.f;
                    ushort4 pk;
                    {
                        const float xn  = x[nf][0] * rms * w4[nf].x;
                        const float rot = sgn * x[pn][0] * rms * w4[pn].x;
                        pk.x = f2bf(xn * cc[0] + rot * sn[0]);
                    }
                    {
                        const float xn  = x[nf][1] * rms * w4[nf].y;
                        const float rot = sgn * x[pn][1] * rms * w4[pn].y;
                        pk.y = f2bf(xn * cc[1] + rot * sn[1]);
                    }
                    {
                        const float xn  = x[nf][2] * rms * w4[nf].z;
                        const float rot = sgn * x[pn][2] * rms * w4[pn].z;
                        pk.z = f2bf(xn * cc[2] + rot * sn[2]);
                    }
                    {
                        const float xn  = x[nf][3] * rms * w4[nf].w;
                        const float rot = sgn * x[pn][3] * rms * w4[pn].w;
                        pk.w = f2bf(xn * cc[3] + rot * sn[3]);
                    }
                    *(ushort4*)(outb + nf * 16) = pk;
                }
            }
        }
    } else {
        // V: D[col = feature][regs = token] -> Vt[bh][d][n] (dim-major)
        const int hg = ((n0 & 1023) + wc * 64) >> 6;
        #pragma unroll
        for (int nf = 0; nf < 4; ++nf) {
            const int d = nf * 16 + fr;
            #pragma unroll
            for (int mf = 0; mf < 8; ++mf) {
                const int mb = m0 + wr * 128 + mf * 16 + rb;
                if (mb < NROWS) {
                    const int bb = mb / NTOK, n = mb - bb * NTOK;
                    ushort4 pk;
                    pk.x = f2bf(acc[mf][nf][0]);
                    pk.y = f2bf(acc[mf][nf][1]);
                    pk.z = f2bf(acc[mf][nf][2]);
                    pk.w = f2bf(acc[mf][nf][3]);
                    *(ushort4*)(QKV + 2L * QKV_ELEMS +
                        ((long)((bb * 16 + hg) * 64 + d)) * NTOK + n) = pk;
                }
            }
        }
    }
#undef SA
#undef SB
#undef WAIT_LGKM0
#undef WAIT_VM6
#undef WAIT_VM0
#undef READ_AF
#undef MFMA_PHASE
}

// ---------------------------------------------------------------------------
// Merged attention (unchanged).
// ---------------------------------------------------------------------------
__global__ __launch_bounds__(256) void attn_kernel(
    const ushort_t* __restrict__ Qb, const ushort_t* __restrict__ Kb,
    const ushort_t* __restrict__ Vt, ushort_t* __restrict__ AO)
{
    __shared__ __align__(16) ushort_t KP_s[256 * 72];

    const int tid = threadIdx.x;
    const int wave = tid >> 6, lane = tid & 63;
    const int m_ = lane & 15, quad = lane >> 4;
    const int nb = wave * 64;
    const int d0 = wave * 16;

    bf16x8 ones;
    #pragma unroll
    for (int e = 0; e < 8; ++e) ones[e] = (__bf16)1.0f;

    if (blockIdx.x >= 128) {
        const int blk = blockIdx.x - 128;
        const int bh = blk & 127, qr = blk >> 7;
        const int b = bh >> 4, h = bh & 15;

        int r0 = qr - 3; if (r0 < 0) r0 = 0;
        int r1 = qr + 3; if (r1 > 31) r1 = 31;
        const int limit = 8 + (r1 - r0 + 1) * 32;

        const ushort_t* Qg  = Qb + ((long)bh * NTOK + 8 + qr * 32) * 64;
        const ushort_t* Kg  = Kb + (long)bh * NTOK * 64;
        const ushort_t* Vtg = Vt + (long)bh * 64 * NTOK;

        bf16x8 af[2][2];
        #pragma unroll
        for (int mt = 0; mt < 2; ++mt)
            #pragma unroll
            for (int ks = 0; ks < 2; ++ks)
                af[mt][ks] = *(const bf16x8*)(Qg + (mt * 16 + m_) * 64 + ks * 32 + quad * 8);

        bf16x8 bv[8];
        #pragma unroll
        for (int ks = 0; ks < 8; ++ks) {
            const int slot0 = ks * 32 + quad * 8;
            int tok0;
            if (slot0 >= limit) tok0 = 0;
            else if (slot0 < 8) tok0 = slot0;
            else tok0 = 8 + r0 * 32 + (slot0 - 8);
            bv[ks] = *(const bf16x8*)(Vtg + (long)(d0 + m_) * NTOK + tok0);
        }

        for (int c = tid; c < limit * 8; c += 256) {
            const int slot = c >> 3, c8 = (c & 7) * 8;
            const int tok = slot + (slot >= 8 ? r0 * 32 : 0);
            *(bf16x8*)&KP_s[slot * 72 + c8] = *(const bf16x8*)(Kg + (long)tok * 64 + c8);
        }
        __syncthreads();

        bf16x8 bfr[4][2];
        #pragma unroll
        for (int nt = 0; nt < 4; ++nt)
            #pragma unroll
            for (int ks = 0; ks < 2; ++ks)
                bfr[nt][ks] = *(const bf16x8*)&KP_s[(nb + nt * 16 + m_) * 72 + ks * 32 + quad * 8];

        f32x4 sacc[2][4] = {};
        #pragma unroll
        for (int mt = 0; mt < 2; ++mt)
            #pragma unroll
            for (int nt = 0; nt < 4; ++nt) {
                sacc[mt][nt] = __builtin_amdgcn_mfma_f32_16x16x32_bf16(
                    af[mt][0], bfr[nt][0], sacc[mt][nt], 0, 0, 0);
                sacc[mt][nt] = __builtin_amdgcn_mfma_f32_16x16x32_bf16(
                    af[mt][1], bfr[nt][1], sacc[mt][nt], 0, 0, 0);
            }
        __syncthreads();

        #pragma unroll
        for (int mt = 0; mt < 2; ++mt)
            #pragma unroll
            for (int nt = 0; nt < 4; ++nt) {
                const int slot = nb + nt * 16 + m_;
                const int kc = (slot - 8) & 31;
                #pragma unroll
                for (int reg = 0; reg < 4; ++reg) {
                    const int qm = mt * 16 + quad * 4 + reg;
                    const bool val = (slot < 8) ||
                        ((slot < limit) && ((unsigned)(kc - qm + 3) <= 6u));
                    const float p = val ? __expf(sacc[mt][nt][reg] * 0.125f) : 0.f;
                    KP_s[qm * 280 + slot] = f2bf(p);
                }
            }
        __syncthreads();

        f32x4 oacc[2] = {}, lacc[2] = {};
        #pragma unroll
        for (int ks = 0; ks < 8; ++ks) {
            #pragma unroll
            for (int mt = 0; mt < 2; ++mt) {
                const bf16x8 ap = *(const bf16x8*)&KP_s[(mt * 16 + m_) * 280 + ks * 32 + quad * 8];
                oacc[mt] = __builtin_amdgcn_mfma_f32_16x16x32_bf16(ap, bv[ks], oacc[mt], 0, 0, 0);
                lacc[mt] = __builtin_amdgcn_mfma_f32_16x16x32_bf16(ap, ones,   lacc[mt], 0, 0, 0);
            }
        }
        #pragma unroll
        for (int mt = 0; mt < 2; ++mt)
            #pragma unroll
            for (int reg = 0; reg < 4; ++reg) {
                const int qm = mt * 16 + quad * 4 + reg;
                const int tok = 8 + qr * 32 + qm;
                AO[((long)(b * NTOK + tok)) * DIMC + h * 64 + d0 + m_] =
                    f2bf(oacc[mt][reg] / lacc[mt][reg]);
            }
    } else {
        const int bh = blockIdx.x;
        const int b = bh >> 4, h = bh & 15;
        const ushort_t* Kg  = Kb + (long)bh * NTOK * 64;
        const ushort_t* Vtg = Vt + (long)bh * 64 * NTOK;

        bf16x8 afs[2];
        if (m_ < 8) {
            #pragma unroll
            for (int ks = 0; ks < 2; ++ks)
                afs[ks] = *(const bf16x8*)(Qb + ((long)bh * NTOK + m_) * 64 + ks * 32 + quad * 8);
        } else {
            #pragma unroll
            for (int ks = 0; ks < 2; ++ks)
                #pragma unroll
                for (int e = 0; e < 8; ++e) afs[ks][e] = (__bf16)0.f;
        }

        f32x4 oacc = {}, lacc = {};
        for (int ch = 0; ch < 5; ++ch) {
            const int tok0 = ch * 256;
            const int limit = (NTOK - tok0 < 256) ? (NTOK - tok0) : 256;

            bf16x8 bv[8];
            #pragma unroll
            for (int ks = 0; ks < 8; ++ks) {
                const int slot0 = ks * 32 + quad * 8;
                const int tok = tok0 + ((slot0 < limit) ? slot0 : 0);
                bv[ks] = *(const bf16x8*)(Vtg + (long)(d0 + m_) * NTOK + tok);
            }

            __syncthreads();
            for (int c = tid; c < limit * 8; c += 256) {
                const int slot = c >> 3, c8 = (c & 7) * 8;
                *(bf16x8*)&KP_s[slot * 72 + c8] =
                    *(const bf16x8*)(Kg + (long)(tok0 + slot) * 64 + c8);
            }
            __syncthreads();

            bf16x8 bfr[4][2];
            #pragma unroll
            for (int nt = 0; nt < 4; ++nt)
                #pragma unroll
                for (int ks = 0; ks < 2; ++ks)
                    bfr[nt][ks] = *(const bf16x8*)&KP_s[(nb + nt * 16 + m_) * 72 + ks * 32 + quad * 8];
            f32x4 sacc[4] = {};
            #pragma unroll
            for (int nt = 0; nt < 4; ++nt) {
                sacc[nt] = __builtin_amdgcn_mfma_f32_16x16x32_bf16(afs[0], bfr[nt][0], sacc[nt], 0, 0, 0);
                sacc[nt] = __builtin_amdgcn_mfma_f32_16x16x32_bf16(afs[1], bfr[nt][1], sacc[nt], 0, 0, 0);
            }
            __syncthreads();

            #pragma unroll
            for (int nt = 0; nt < 4; ++nt) {
                const int slot = nb + nt * 16 + m_;
                const bool val = (slot < limit);
                #pragma unroll
                for (int reg = 0; reg < 4; ++reg) {
                    const int qm = quad * 4 + reg;
                    const float p = val ? __expf(sacc[nt][reg] * 0.125f) : 0.f;
                    KP_s[qm * 280 + slot] = f2bf(p);
                }
            }
            __syncthreads();

            #pragma unroll
            for (int ks = 0; ks < 8; ++ks) {
                const bf16x8 ap = *(const bf16x8*)&KP_s[m_ * 280 + ks * 32 + quad * 8];
                oacc = __builtin_amdgcn_mfma_f32_16x16x32_bf16(ap, bv[ks], oacc, 0, 0, 0);
                lacc = __builtin_amdgcn_mfma_f32_16x16x32_bf16(ap, ones,   lacc, 0, 0, 0);
            }
        }

        #pragma unroll
        for (int reg = 0; reg < 4; ++reg) {
            const int qm = quad * 4 + reg;
            if (qm < 8) {
                AO[((long)(b * NTOK + qm)) * DIMC + h * 64 + d0 + m_] =
                    f2bf(oacc[reg] / lacc[reg]);
            }
        }
    }
}

extern "C" void kernel_launch(void* const* d_in, const int* in_sizes, int n_in,
                              void* d_out, int out_size, void* d_ws, size_t ws_size,
                              hipStream_t stream) {
    const float* X    = (const float*)d_in[0];
    const float* fc   = (const float*)d_in[1];
    const float* fs   = (const float*)d_in[2];
    const float* qkvw = (const float*)d_in[3];
    const float* outw = (const float*)d_in[4];
    const float* nqw  = (const float*)d_in[5];
    const float* nkw  = (const float*)d_in[6];

    ushort_t* Qb  = (ushort_t*)d_ws;
    ushort_t* Kb  = Qb + QKV_ELEMS;
    ushort_t* Vt  = Kb + QKV_ELEMS;
    ushort_t* AO  = Vt + QKV_ELEMS;
    ushort_t* Xb  = AO + QKV_ELEMS;
    ushort_t* Wqb = Xb + XE;
    ushort_t* Wob = Wqb + QWE;
    float* Out = (float*)d_out;

    cvt_kernel<<<6176, 256, 0, stream>>>(X, qkvw, outw, Xb, Wqb, Wob);
    gemm256_kernel<0><<<dim3(12, 33), 512, 0, stream>>>(Xb, Wqb, Qb, nullptr,
                                                        fc, fs, nqw, nkw);
    attn_kernel<<<4224, 256, 0, stream>>>(Qb, Kb, Vt, AO);
    gemm256_kernel<1><<<dim3(4, 33), 512, 0, stream>>>(AO, Wob, nullptr, Out,
                                                       fc, fs, nqw, nkw);
}

// Round 5
// 254.896 us; speedup vs baseline: 1.3409x; 1.3182x over previous
//
#include <hip/hip_runtime.h>
#include <hip/hip_bf16.h>

typedef unsigned short ushort_t;
typedef __bf16 bf16x8 __attribute__((ext_vector_type(8)));
typedef float f32x4 __attribute__((ext_vector_type(4)));
typedef float f32x8 __attribute__((ext_vector_type(8)));

#define NTOK 1032
#define NROWS 8256       // B*N = 8*1032
#define DIMC 1024
#define QKV_ELEMS 8454144  // 8*16*1032*64 elements per tensor
#define XE 8454144         // X elements (8256*1024)
#define QWE 3145728        // qkv_w elements (3072*1024)
#define OWE 1048576        // out_w elements (1024*1024)

__device__ __forceinline__ float bf2f(ushort_t u) {
    union { unsigned int i; float f; } v; v.i = ((unsigned int)u) << 16; return v.f;
}
__device__ __forceinline__ ushort_t f2bf(float f) {
    union { float f; unsigned int i; } v; v.f = f;
    unsigned int r = v.i + 0x7fffu + ((v.i >> 16) & 1u);
    return (ushort_t)(r >> 16);
}
__device__ __forceinline__ bf16x8 cvt8(const float* p) {
    const float4 a = *(const float4*)p;
    const float4 b = *(const float4*)(p + 4);
    bf16x8 r;
    r[0] = (__bf16)a.x; r[1] = (__bf16)a.y; r[2] = (__bf16)a.z; r[3] = (__bf16)a.w;
    r[4] = (__bf16)b.x; r[5] = (__bf16)b.y; r[6] = (__bf16)b.z; r[7] = (__bf16)b.w;
    return r;
}
__device__ __forceinline__ void load_lds16(const ushort_t* g, ushort_t* l) {
    __builtin_amdgcn_global_load_lds(
        (const __attribute__((address_space(1))) unsigned int*)g,
        (__attribute__((address_space(3))) unsigned int*)l, 16, 0, 0);
}

// ---------------------------------------------------------------------------
// fp32 -> bf16 pre-conversion of X, qkv_w, out_w (RNE).
// ---------------------------------------------------------------------------
__global__ __launch_bounds__(256) void cvt_kernel(
    const float* __restrict__ X, const float* __restrict__ Wq,
    const float* __restrict__ Wo,
    ushort_t* __restrict__ Xb, ushort_t* __restrict__ Wqb,
    ushort_t* __restrict__ Wob)
{
    const long i8 = ((long)blockIdx.x * 256 + threadIdx.x) * 8;
    const float* src;
    ushort_t* dst;
    long off;
    if (i8 < XE)            { src = X;  dst = Xb;  off = i8; }
    else if (i8 < XE + QWE) { src = Wq; dst = Wqb; off = i8 - XE; }
    else                    { src = Wo; dst = Wob; off = i8 - XE - QWE; }
    *(bf16x8*)(dst + off) = cvt8(src + off);
}

// ---------------------------------------------------------------------------
// 256x256 deep-pipelined GEMM.
//   8 waves (2M x 4N), per-wave 128x64 C. BK=64, 2 LDS buffers.
//   Fused RMSNorm + RoPE in the Q/K epilogue. ROUND-5 FIX: rounds 3/4 put
//   the heavy fused body inside "#pragma unroll for (mf)"; the compiler did
//   not fully unroll -> acc[mf][..] runtime-indexed -> the 128-reg
//   accumulator was homed to SCRATCH (rule #20). Evidence: MfmaUtil
//   diluted exactly as 23%*91us/dur, +19MB FETCH / +39MB WRITE of scratch
//   traffic, 1% occupancy on the cold dispatch. Fix: per-mf macro with
//   LITERAL mf (QK_MF(0..7)) so every acc index is compile-time, and the
//   RMS weight is folded into the staged table (U[r][f] = (w[f]*cos,
//   w[f^32]*sin)) to cut live registers.
//   MODE 0: QKV projection (x<8 Q/K swapped + fused norm/rope; x>=8 V->Vt).
//   MODE 1: out-projection (swap always, fp32 float4 stores), grid 4x33.
// ---------------------------------------------------------------------------
template<int MODE>
__global__ __launch_bounds__(512, 2) void gemm256_kernel(
    const ushort_t* __restrict__ A, const ushort_t* __restrict__ W,
    ushort_t* __restrict__ QKV, float* __restrict__ Out,
    const float* __restrict__ cosb, const float* __restrict__ sinb,
    const float* __restrict__ nqw, const float* __restrict__ nkw)
{
    constexpr int SMEM_BYTES = (MODE == 0) ? 135168 : 131072;
    __shared__ __align__(16) unsigned char SMEM[SMEM_BYTES];
    ushort_t* A_lds = (ushort_t*)SMEM;              // 2 buf x 256 x 64 (64KB)
    ushort_t* B_lds = (ushort_t*)(SMEM + 65536);    // 64KB

    const int tid  = threadIdx.x;
    const int wave = tid >> 6, lane = tid & 63;
    const int wr = wave >> 2, wc = wave & 3;        // 2 x 4 wave grid
    const int fr = lane & 15, quad = lane >> 4;
    const int m0 = blockIdx.y * 256;
    const int n0 = blockIdx.x * 256;
    const bool swap = (MODE == 1) || (blockIdx.x < 8);

    // ---- staging offsets: slot s = ld*512+tid; row=s>>3, chunk=s&7;
    //      global k-chunk = (s&7) ^ (row&7)  (involution swizzle) ----
    int aoff[4], boff[4];
    #pragma unroll
    for (int ld = 0; ld < 4; ++ld) {
        const int s   = ld * 512 + tid;
        const int row = s >> 3;
        const int kc  = ((s & 7) ^ (row & 7)) * 8;
        int ar = m0 + row; if (ar > NROWS - 1) ar = NROWS - 1;
        aoff[ld] = ar * DIMC + kc;
        boff[ld] = (n0 + row) * DIMC + kc;          // always in-bounds for W
    }

    // ---- fragment read offsets (swizzled chunk, constant per lane) ----
    const int ck0 = (quad ^ (fr & 7)) * 8;          // k-sub 0 (k 0..31)
    const int ck1 = ((quad + 4) ^ (fr & 7)) * 8;    // k-sub 1 (k 32..63)
    const int abase = (wr * 128 + fr) * 64;
    const int bbase = (wc * 64 + fr) * 64;

    f32x4 acc[8][4] = {};

#define SA(ld, t, c) load_lds16(A + aoff[ld] + (t) * 64, \
                                &A_lds[(c) * 16384 + ((ld) * 512 + tid) * 8])
#define SB(ld, t, c) load_lds16(W + boff[ld] + (t) * 64, \
                                &B_lds[(c) * 16384 + ((ld) * 512 + tid) * 8])
#define WAIT_LGKM0 asm volatile("s_waitcnt lgkmcnt(0)" ::: "memory")
#define WAIT_VM6   asm volatile("s_waitcnt vmcnt(6)"  ::: "memory")
#define WAIT_VM0   asm volatile("s_waitcnt vmcnt(0)"  ::: "memory")

#define READ_AF(p) \
    af[0][0] = *(const bf16x8*)&A_lds[cb + abase + ((p) * 2 + 0) * 1024 + ck0]; \
    af[0][1] = *(const bf16x8*)&A_lds[cb + abase + ((p) * 2 + 0) * 1024 + ck1]; \
    af[1][0] = *(const bf16x8*)&A_lds[cb + abase + ((p) * 2 + 1) * 1024 + ck0]; \
    af[1][1] = *(const bf16x8*)&A_lds[cb + abase + ((p) * 2 + 1) * 1024 + ck1];

#define MFMA_PHASE(p) \
    __builtin_amdgcn_s_setprio(1); \
    if (swap) { \
        _Pragma("unroll") \
        for (int mfi = 0; mfi < 2; ++mfi) \
            _Pragma("unroll") \
            for (int nf = 0; nf < 4; ++nf) { \
                acc[(p) * 2 + mfi][nf] = __builtin_amdgcn_mfma_f32_16x16x32_bf16( \
                    bfrag[nf][0], af[mfi][0], acc[(p) * 2 + mfi][nf], 0, 0, 0); \
                acc[(p) * 2 + mfi][nf] = __builtin_amdgcn_mfma_f32_16x16x32_bf16( \
                    bfrag[nf][1], af[mfi][1], acc[(p) * 2 + mfi][nf], 0, 0, 0); \
            } \
    } else { \
        _Pragma("unroll") \
        for (int mfi = 0; mfi < 2; ++mfi) \
            _Pragma("unroll") \
            for (int nf = 0; nf < 4; ++nf) { \
                acc[(p) * 2 + mfi][nf] = __builtin_amdgcn_mfma_f32_16x16x32_bf16( \
                    af[mfi][0], bfrag[nf][0], acc[(p) * 2 + mfi][nf], 0, 0, 0); \
                acc[(p) * 2 + mfi][nf] = __builtin_amdgcn_mfma_f32_16x16x32_bf16( \
                    af[mfi][1], bfrag[nf][1], acc[(p) * 2 + mfi][nf], 0, 0, 0); \
            } \
    } \
    __builtin_amdgcn_s_setprio(0);

    // ---- prologue: tile0 complete (8), tile1 B+A-lo (6) ----
    SB(0, 0, 0); SB(1, 0, 0); SB(2, 0, 0); SB(3, 0, 0);
    SA(0, 0, 0); SA(1, 0, 0); SA(2, 0, 0); SA(3, 0, 0);
    SB(0, 1, 1); SB(1, 1, 1); SB(2, 1, 1); SB(3, 1, 1);
    SA(0, 1, 1); SA(2, 1, 1);               // ld0,ld2 = rows 0-63 & 128-191
    WAIT_VM6;                               // tile0 done; tile1's 6 in flight
    __builtin_amdgcn_s_barrier();

    for (int t = 0; t < 16; ++t) {
        const int c = t & 1, o = c ^ 1;
        const int cb = c * 16384;
        bf16x8 bfrag[4][2];
        bf16x8 af[2][2];

        // ---- phase 0: B frags + A quadrant 0 ----
        #pragma unroll
        for (int nf = 0; nf < 4; ++nf) {
            bfrag[nf][0] = *(const bf16x8*)&B_lds[cb + bbase + nf * 1024 + ck0];
            bfrag[nf][1] = *(const bf16x8*)&B_lds[cb + bbase + nf * 1024 + ck1];
        }
        READ_AF(0);
        if (t < 15) { SA(1, t + 1, o); SA(3, t + 1, o); }
        __builtin_amdgcn_s_barrier();
        WAIT_LGKM0; __builtin_amdgcn_sched_barrier(0);
        MFMA_PHASE(0);
        __builtin_amdgcn_s_barrier();       // T0: B(cur) now dead

        // ---- phase 1 ----
        READ_AF(1);
        if (t < 14) { SB(0, t + 2, c); SB(1, t + 2, c);
                      SB(2, t + 2, c); SB(3, t + 2, c); }
        __builtin_amdgcn_s_barrier();
        WAIT_LGKM0; __builtin_amdgcn_sched_barrier(0);
        MFMA_PHASE(1);
        __builtin_amdgcn_s_barrier();       // T1: A-lo(cur) now dead

        // ---- phase 2 ----
        READ_AF(2);
        if (t < 14) { SA(0, t + 2, c); SA(2, t + 2, c); }
        __builtin_amdgcn_s_barrier();
        WAIT_LGKM0; __builtin_amdgcn_sched_barrier(0);
        MFMA_PHASE(2);
        // no trailing barrier: nothing stages into regions read in p2/p3
        // until after the boundary barrier.

        // ---- phase 3 ----
        READ_AF(3);
        __builtin_amdgcn_s_barrier();
        WAIT_LGKM0; __builtin_amdgcn_sched_barrier(0);
        MFMA_PHASE(3);

        // ---- tile boundary: next buffer complete, 6 loads stay in flight ----
        if (t < 14)       { WAIT_VM6; __builtin_amdgcn_s_barrier(); }
        else if (t == 14) { WAIT_VM0; __builtin_amdgcn_s_barrier(); }
    }

    // ---- epilogue ----
    const int rb = quad * 4;
    if (MODE == 1) {
        // out proj: D[col = token m][regs = feature] -> float4 stores
        #pragma unroll
        for (int mf = 0; mf < 8; ++mf) {
            const int m = m0 + wr * 128 + mf * 16 + fr;
            if (m < NROWS) {
                #pragma unroll
                for (int nf = 0; nf < 4; ++nf) {
                    const int o_ = n0 + wc * 64 + nf * 16 + rb;
                    float4 pk;
                    pk.x = acc[mf][nf][0];
                    pk.y = acc[mf][nf][1];
                    pk.z = acc[mf][nf][2];
                    pk.w = acc[mf][nf][3];
                    *(float4*)(Out + (long)m * DIMC + o_) = pk;
                }
            }
        }
    } else if (swap) {
        // Q/K: D[col = token m][regs = feature]; wave-col (wc) = one head.
        // Fused RMSNorm + RoPE. Table staged to LDS with the norm weight
        // folded in: U[r][f] = (w[f]*cos[n][f], w[f^32]*sin[n][f]).
        const int part   = n0 >> 10;                 // 0 = Q, 1 = K
        const int hgbase = ((n0 & 1023) + wc * 64) >> 6;
        const float* wtab = (part == 0) ? nqw : nkw;

        float* T = (float*)SMEM;
        __syncthreads();                     // all waves done with GEMM LDS
        for (int e = tid; e < 256 * 16; e += 512) {
            const int row = e >> 4, seg = e & 15;
            const int mm  = m0 + row;
            const int bb2 = mm / NTOK;
            const int n2  = mm - bb2 * NTOK;  // <= 1031 even for dead rows
            const float4 c4 = *(const float4*)(cosb + n2 * 64 + seg * 4);
            const float4 s4 = *(const float4*)(sinb + n2 * 64 + seg * 4);
            const float4 wf = *(const float4*)(wtab + seg * 4);
            const float4 wp = *(const float4*)(wtab + ((seg ^ 8) * 4));
            float* dst = T + row * 132 + seg * 8;
            ((float2*)dst)[0] = make_float2(c4.x * wf.x, s4.x * wp.x);
            ((float2*)dst)[1] = make_float2(c4.y * wf.y, s4.y * wp.y);
            ((float2*)dst)[2] = make_float2(c4.z * wf.z, s4.z * wp.z);
            ((float2*)dst)[3] = make_float2(c4.w * wf.w, s4.w * wp.w);
        }
        __syncthreads();

        // Per-mf macro: LITERAL mf -> all acc indices compile-time (rule #20).
#define QK_NF(MF, NF, PN, SGN) { \
        const float4 q0 = *(const float4*)(trow + ((NF) * 16 + rb) * 2); \
        const float4 q1 = *(const float4*)(trow + ((NF) * 16 + rb) * 2 + 4); \
        ushort4 pk; \
        pk.x = f2bf(rms * (acc[MF][NF][0] * q0.x + (SGN) * acc[MF][PN][0] * q0.y)); \
        pk.y = f2bf(rms * (acc[MF][NF][1] * q0.z + (SGN) * acc[MF][PN][1] * q0.w)); \
        pk.z = f2bf(rms * (acc[MF][NF][2] * q1.x + (SGN) * acc[MF][PN][2] * q1.y)); \
        pk.w = f2bf(rms * (acc[MF][NF][3] * q1.z + (SGN) * acc[MF][PN][3] * q1.w)); \
        *(ushort4*)(outb + (NF) * 16) = pk; }

#define QK_MF(MF) { \
        const int rr = wr * 128 + (MF) * 16 + fr; \
        const int m  = m0 + rr; \
        if (m < NROWS) { \
            const int bb = m / NTOK, n = m - bb * NTOK; \
            float ss = 0.f; \
            _Pragma("unroll") \
            for (int nf = 0; nf < 4; ++nf) { \
                ss += acc[MF][nf][0] * acc[MF][nf][0]; \
                ss += acc[MF][nf][1] * acc[MF][nf][1]; \
                ss += acc[MF][nf][2] * acc[MF][nf][2]; \
                ss += acc[MF][nf][3] * acc[MF][nf][3]; \
            } \
            ss += __shfl_xor(ss, 16, 64); \
            ss += __shfl_xor(ss, 32, 64); \
            const float rms = rsqrtf(ss * (1.0f / 64.0f) + 1e-6f); \
            const float* trow = T + rr * 132; \
            ushort_t* outb = QKV + (long)part * QKV_ELEMS + \
                ((long)(bb * 16 + hgbase) * NTOK + n) * 64 + rb; \
            QK_NF(MF, 0, 2, -1.f) \
            QK_NF(MF, 1, 3, -1.f) \
            QK_NF(MF, 2, 0,  1.f) \
            QK_NF(MF, 3, 1,  1.f) \
        } }

        QK_MF(0) QK_MF(1) QK_MF(2) QK_MF(3)
        QK_MF(4) QK_MF(5) QK_MF(6) QK_MF(7)
#undef QK_MF
#undef QK_NF
    } else {
        // V: D[col = feature][regs = token] -> Vt[bh][d][n] (dim-major)
        const int hg = ((n0 & 1023) + wc * 64) >> 6;
        #pragma unroll
        for (int nf = 0; nf < 4; ++nf) {
            const int d = nf * 16 + fr;
            #pragma unroll
            for (int mf = 0; mf < 8; ++mf) {
                const int mb = m0 + wr * 128 + mf * 16 + rb;
                if (mb < NROWS) {
                    const int bb = mb / NTOK, n = mb - bb * NTOK;
                    ushort4 pk;
                    pk.x = f2bf(acc[mf][nf][0]);
                    pk.y = f2bf(acc[mf][nf][1]);
                    pk.z = f2bf(acc[mf][nf][2]);
                    pk.w = f2bf(acc[mf][nf][3]);
                    *(ushort4*)(QKV + 2L * QKV_ELEMS +
                        ((long)((bb * 16 + hg) * 64 + d)) * NTOK + n) = pk;
                }
            }
        }
    }
#undef SA
#undef SB
#undef WAIT_LGKM0
#undef WAIT_VM6
#undef WAIT_VM0
#undef READ_AF
#undef MFMA_PHASE
}

// ---------------------------------------------------------------------------
// Merged attention (unchanged).
// ---------------------------------------------------------------------------
__global__ __launch_bounds__(256) void attn_kernel(
    const ushort_t* __restrict__ Qb, const ushort_t* __restrict__ Kb,
    const ushort_t* __restrict__ Vt, ushort_t* __restrict__ AO)
{
    __shared__ __align__(16) ushort_t KP_s[256 * 72];

    const int tid = threadIdx.x;
    const int wave = tid >> 6, lane = tid & 63;
    const int m_ = lane & 15, quad = lane >> 4;
    const int nb = wave * 64;
    const int d0 = wave * 16;

    bf16x8 ones;
    #pragma unroll
    for (int e = 0; e < 8; ++e) ones[e] = (__bf16)1.0f;

    if (blockIdx.x >= 128) {
        const int blk = blockIdx.x - 128;
        const int bh = blk & 127, qr = blk >> 7;
        const int b = bh >> 4, h = bh & 15;

        int r0 = qr - 3; if (r0 < 0) r0 = 0;
        int r1 = qr + 3; if (r1 > 31) r1 = 31;
        const int limit = 8 + (r1 - r0 + 1) * 32;

        const ushort_t* Qg  = Qb + ((long)bh * NTOK + 8 + qr * 32) * 64;
        const ushort_t* Kg  = Kb + (long)bh * NTOK * 64;
        const ushort_t* Vtg = Vt + (long)bh * 64 * NTOK;

        bf16x8 af[2][2];
        #pragma unroll
        for (int mt = 0; mt < 2; ++mt)
            #pragma unroll
            for (int ks = 0; ks < 2; ++ks)
                af[mt][ks] = *(const bf16x8*)(Qg + (mt * 16 + m_) * 64 + ks * 32 + quad * 8);

        bf16x8 bv[8];
        #pragma unroll
        for (int ks = 0; ks < 8; ++ks) {
            const int slot0 = ks * 32 + quad * 8;
            int tok0;
            if (slot0 >= limit) tok0 = 0;
            else if (slot0 < 8) tok0 = slot0;
            else tok0 = 8 + r0 * 32 + (slot0 - 8);
            bv[ks] = *(const bf16x8*)(Vtg + (long)(d0 + m_) * NTOK + tok0);
        }

        for (int c = tid; c < limit * 8; c += 256) {
            const int slot = c >> 3, c8 = (c & 7) * 8;
            const int tok = slot + (slot >= 8 ? r0 * 32 : 0);
            *(bf16x8*)&KP_s[slot * 72 + c8] = *(const bf16x8*)(Kg + (long)tok * 64 + c8);
        }
        __syncthreads();

        bf16x8 bfr[4][2];
        #pragma unroll
        for (int nt = 0; nt < 4; ++nt)
            #pragma unroll
            for (int ks = 0; ks < 2; ++ks)
                bfr[nt][ks] = *(const bf16x8*)&KP_s[(nb + nt * 16 + m_) * 72 + ks * 32 + quad * 8];

        f32x4 sacc[2][4] = {};
        #pragma unroll
        for (int mt = 0; mt < 2; ++mt)
            #pragma unroll
            for (int nt = 0; nt < 4; ++nt) {
                sacc[mt][nt] = __builtin_amdgcn_mfma_f32_16x16x32_bf16(
                    af[mt][0], bfr[nt][0], sacc[mt][nt], 0, 0, 0);
                sacc[mt][nt] = __builtin_amdgcn_mfma_f32_16x16x32_bf16(
                    af[mt][1], bfr[nt][1], sacc[mt][nt], 0, 0, 0);
            }
        __syncthreads();

        #pragma unroll
        for (int mt = 0; mt < 2; ++mt)
            #pragma unroll
            for (int nt = 0; nt < 4; ++nt) {
                const int slot = nb + nt * 16 + m_;
                const int kc = (slot - 8) & 31;
                #pragma unroll
                for (int reg = 0; reg < 4; ++reg) {
                    const int qm = mt * 16 + quad * 4 + reg;
                    const bool val = (slot < 8) ||
                        ((slot < limit) && ((unsigned)(kc - qm + 3) <= 6u));
                    const float p = val ? __expf(sacc[mt][nt][reg] * 0.125f) : 0.f;
                    KP_s[qm * 280 + slot] = f2bf(p);
                }
            }
        __syncthreads();

        f32x4 oacc[2] = {}, lacc[2] = {};
        #pragma unroll
        for (int ks = 0; ks < 8; ++ks) {
            #pragma unroll
            for (int mt = 0; mt < 2; ++mt) {
                const bf16x8 ap = *(const bf16x8*)&KP_s[(mt * 16 + m_) * 280 + ks * 32 + quad * 8];
                oacc[mt] = __builtin_amdgcn_mfma_f32_16x16x32_bf16(ap, bv[ks], oacc[mt], 0, 0, 0);
                lacc[mt] = __builtin_amdgcn_mfma_f32_16x16x32_bf16(ap, ones,   lacc[mt], 0, 0, 0);
            }
        }
        #pragma unroll
        for (int mt = 0; mt < 2; ++mt)
            #pragma unroll
            for (int reg = 0; reg < 4; ++reg) {
                const int qm = mt * 16 + quad * 4 + reg;
                const int tok = 8 + qr * 32 + qm;
                AO[((long)(b * NTOK + tok)) * DIMC + h * 64 + d0 + m_] =
                    f2bf(oacc[mt][reg] / lacc[mt][reg]);
            }
    } else {
        const int bh = blockIdx.x;
        const int b = bh >> 4, h = bh & 15;
        const ushort_t* Kg  = Kb + (long)bh * NTOK * 64;
        const ushort_t* Vtg = Vt + (long)bh * 64 * NTOK;

        bf16x8 afs[2];
        if (m_ < 8) {
            #pragma unroll
            for (int ks = 0; ks < 2; ++ks)
                afs[ks] = *(const bf16x8*)(Qb + ((long)bh * NTOK + m_) * 64 + ks * 32 + quad * 8);
        } else {
            #pragma unroll
            for (int ks = 0; ks < 2; ++ks)
                #pragma unroll
                for (int e = 0; e < 8; ++e) afs[ks][e] = (__bf16)0.f;
        }

        f32x4 oacc = {}, lacc = {};
        for (int ch = 0; ch < 5; ++ch) {
            const int tok0 = ch * 256;
            const int limit = (NTOK - tok0 < 256) ? (NTOK - tok0) : 256;

            bf16x8 bv[8];
            #pragma unroll
            for (int ks = 0; ks < 8; ++ks) {
                const int slot0 = ks * 32 + quad * 8;
                const int tok = tok0 + ((slot0 < limit) ? slot0 : 0);
                bv[ks] = *(const bf16x8*)(Vtg + (long)(d0 + m_) * NTOK + tok);
            }

            __syncthreads();
            for (int c = tid; c < limit * 8; c += 256) {
                const int slot = c >> 3, c8 = (c & 7) * 8;
                *(bf16x8*)&KP_s[slot * 72 + c8] =
                    *(const bf16x8*)(Kg + (long)(tok0 + slot) * 64 + c8);
            }
            __syncthreads();

            bf16x8 bfr[4][2];
            #pragma unroll
            for (int nt = 0; nt < 4; ++nt)
                #pragma unroll
                for (int ks = 0; ks < 2; ++ks)
                    bfr[nt][ks] = *(const bf16x8*)&KP_s[(nb + nt * 16 + m_) * 72 + ks * 32 + quad * 8];
            f32x4 sacc[4] = {};
            #pragma unroll
            for (int nt = 0; nt < 4; ++nt) {
                sacc[nt] = __builtin_amdgcn_mfma_f32_16x16x32_bf16(afs[0], bfr[nt][0], sacc[nt], 0, 0, 0);
                sacc[nt] = __builtin_amdgcn_mfma_f32_16x16x32_bf16(afs[1], bfr[nt][1], sacc[nt], 0, 0, 0);
            }
            __syncthreads();

            #pragma unroll
            for (int nt = 0; nt < 4; ++nt) {
                const int slot = nb + nt * 16 + m_;
                const bool val = (slot < limit);
                #pragma unroll
                for (int reg = 0; reg < 4; ++reg) {
                    const int qm = quad * 4 + reg;
                    const float p = val ? __expf(sacc[nt][reg] * 0.125f) : 0.f;
                    KP_s[qm * 280 + slot] = f2bf(p);
                }
            }
            __syncthreads();

            #pragma unroll
            for (int ks = 0; ks < 8; ++ks) {
                const bf16x8 ap = *(const bf16x8*)&KP_s[m_ * 280 + ks * 32 + quad * 8];
                oacc = __builtin_amdgcn_mfma_f32_16x16x32_bf16(ap, bv[ks], oacc, 0, 0, 0);
                lacc = __builtin_amdgcn_mfma_f32_16x16x32_bf16(ap, ones,   lacc, 0, 0, 0);
            }
        }

        #pragma unroll
        for (int reg = 0; reg < 4; ++reg) {
            const int qm = quad * 4 + reg;
            if (qm < 8) {
                AO[((long)(b * NTOK + qm)) * DIMC + h * 64 + d0 + m_] =
                    f2bf(oacc[reg] / lacc[reg]);
            }
        }
    }
}

extern "C" void kernel_launch(void* const* d_in, const int* in_sizes, int n_in,
                              void* d_out, int out_size, void* d_ws, size_t ws_size,
                              hipStream_t stream) {
    const float* X    = (const float*)d_in[0];
    const float* fc   = (const float*)d_in[1];
    const float* fs   = (const float*)d_in[2];
    const float* qkvw = (const float*)d_in[3];
    const float* outw = (const float*)d_in[4];
    const float* nqw  = (const float*)d_in[5];
    const float* nkw  = (const float*)d_in[6];

    ushort_t* Qb  = (ushort_t*)d_ws;
    ushort_t* Kb  = Qb + QKV_ELEMS;
    ushort_t* Vt  = Kb + QKV_ELEMS;
    ushort_t* AO  = Vt + QKV_ELEMS;
    ushort_t* Xb  = AO + QKV_ELEMS;
    ushort_t* Wqb = Xb + XE;
    ushort_t* Wob = Wqb + QWE;
    float* Out = (float*)d_out;

    cvt_kernel<<<6176, 256, 0, stream>>>(X, qkvw, outw, Xb, Wqb, Wob);
    gemm256_kernel<0><<<dim3(12, 33), 512, 0, stream>>>(Xb, Wqb, Qb, nullptr,
                                                        fc, fs, nqw, nkw);
    attn_kernel<<<4224, 256, 0, stream>>>(Qb, Kb, Vt, AO);
    gemm256_kernel<1><<<dim3(4, 33), 512, 0, stream>>>(AO, Wob, nullptr, Out,
                                                       fc, fs, nqw, nkw);
}

// Round 6
// 249.725 us; speedup vs baseline: 1.3687x; 1.0207x over previous
//
#include <hip/hip_runtime.h>
#include <hip/hip_bf16.h>

typedef unsigned short ushort_t;
typedef __bf16 bf16x8 __attribute__((ext_vector_type(8)));
typedef float f32x4 __attribute__((ext_vector_type(4)));
typedef float f32x8 __attribute__((ext_vector_type(8)));

#define NTOK 1032
#define NROWS 8256       // B*N = 8*1032
#define DIMC 1024
#define QKV_ELEMS 8454144  // 8*16*1032*64 elements per tensor
#define XE 8454144         // X elements (8256*1024)
#define QWE 3145728        // qkv_w elements (3072*1024)
#define OWE 1048576        // out_w elements (1024*1024)

__device__ __forceinline__ float bf2f(ushort_t u) {
    union { unsigned int i; float f; } v; v.i = ((unsigned int)u) << 16; return v.f;
}
__device__ __forceinline__ ushort_t f2bf(float f) {
    union { float f; unsigned int i; } v; v.f = f;
    unsigned int r = v.i + 0x7fffu + ((v.i >> 16) & 1u);
    return (ushort_t)(r >> 16);
}
__device__ __forceinline__ bf16x8 cvt8(const float* p) {
    const float4 a = *(const float4*)p;
    const float4 b = *(const float4*)(p + 4);
    bf16x8 r;
    r[0] = (__bf16)a.x; r[1] = (__bf16)a.y; r[2] = (__bf16)a.z; r[3] = (__bf16)a.w;
    r[4] = (__bf16)b.x; r[5] = (__bf16)b.y; r[6] = (__bf16)b.z; r[7] = (__bf16)b.w;
    return r;
}
__device__ __forceinline__ void load_lds16(const ushort_t* g, ushort_t* l) {
    __builtin_amdgcn_global_load_lds(
        (const __attribute__((address_space(1))) unsigned int*)g,
        (__attribute__((address_space(3))) unsigned int*)l, 16, 0, 0);
}

// ---------------------------------------------------------------------------
// fp32 -> bf16 pre-conversion of X, qkv_w, out_w (RNE).
// ---------------------------------------------------------------------------
__global__ __launch_bounds__(256) void cvt_kernel(
    const float* __restrict__ X, const float* __restrict__ Wq,
    const float* __restrict__ Wo,
    ushort_t* __restrict__ Xb, ushort_t* __restrict__ Wqb,
    ushort_t* __restrict__ Wob)
{
    const long i8 = ((long)blockIdx.x * 256 + threadIdx.x) * 8;
    const float* src;
    ushort_t* dst;
    long off;
    if (i8 < XE)            { src = X;  dst = Xb;  off = i8; }
    else if (i8 < XE + QWE) { src = Wq; dst = Wqb; off = i8 - XE; }
    else                    { src = Wo; dst = Wob; off = i8 - XE - QWE; }
    *(bf16x8*)(dst + off) = cvt8(src + off);
}

// ---------------------------------------------------------------------------
// 256x256 deep-pipelined GEMM, fused RMSNorm+RoPE epilogue (round 5,
// scratch-free). ROUND-6: bijective XCD chunked swizzle (T1/m204) so blocks
// sharing an A panel (consecutive logical n at fixed m) land on the same
// XCD's L2 instead of round-robining across all 8. MODE1's per-XCD working
// set (4 A panels + 4 B panels = 4MB) becomes fully L2-resident.
//   MODE 0: QKV projection (nx<8 Q/K swapped + fused norm/rope; nx>=8 V->Vt).
//   MODE 1: out-projection (swap always, fp32 float4 stores), grid 4x33.
// ---------------------------------------------------------------------------
template<int MODE>
__global__ __launch_bounds__(512, 2) void gemm256_kernel(
    const ushort_t* __restrict__ A, const ushort_t* __restrict__ W,
    ushort_t* __restrict__ QKV, float* __restrict__ Out,
    const float* __restrict__ cosb, const float* __restrict__ sinb,
    const float* __restrict__ nqw, const float* __restrict__ nkw)
{
    constexpr int SMEM_BYTES = (MODE == 0) ? 135168 : 131072;
    __shared__ __align__(16) unsigned char SMEM[SMEM_BYTES];
    ushort_t* A_lds = (ushort_t*)SMEM;              // 2 buf x 256 x 64 (64KB)
    ushort_t* B_lds = (ushort_t*)(SMEM + 65536);    // 64KB

    // ---- bijective XCD chunked swizzle (m204): orig%8 ~ XCD; give each
    //      XCD a contiguous chunk of the logical grid ----
    constexpr int GX  = (MODE == 0) ? 12 : 4;
    constexpr int NWG = GX * 33;
    constexpr int QW  = NWG >> 3, RW = NWG & 7;
    {
    }
    const int orig = blockIdx.y * GX + blockIdx.x;
    const int xcd  = orig & 7, li = orig >> 3;
    const int wgid = (xcd < RW ? xcd * (QW + 1)
                               : RW * (QW + 1) + (xcd - RW) * QW) + li;
    const int bx = wgid % GX, by = wgid / GX;

    const int tid  = threadIdx.x;
    const int wave = tid >> 6, lane = tid & 63;
    const int wr = wave >> 2, wc = wave & 3;        // 2 x 4 wave grid
    const int fr = lane & 15, quad = lane >> 4;
    const int m0 = by * 256;
    const int n0 = bx * 256;
    const bool swap = (MODE == 1) || (bx < 8);

    // ---- staging offsets: slot s = ld*512+tid; row=s>>3, chunk=s&7;
    //      global k-chunk = (s&7) ^ (row&7)  (involution swizzle) ----
    int aoff[4], boff[4];
    #pragma unroll
    for (int ld = 0; ld < 4; ++ld) {
        const int s   = ld * 512 + tid;
        const int row = s >> 3;
        const int kc  = ((s & 7) ^ (row & 7)) * 8;
        int ar = m0 + row; if (ar > NROWS - 1) ar = NROWS - 1;
        aoff[ld] = ar * DIMC + kc;
        boff[ld] = (n0 + row) * DIMC + kc;          // always in-bounds for W
    }

    // ---- fragment read offsets (swizzled chunk, constant per lane) ----
    const int ck0 = (quad ^ (fr & 7)) * 8;          // k-sub 0 (k 0..31)
    const int ck1 = ((quad + 4) ^ (fr & 7)) * 8;    // k-sub 1 (k 32..63)
    const int abase = (wr * 128 + fr) * 64;
    const int bbase = (wc * 64 + fr) * 64;

    f32x4 acc[8][4] = {};

#define SA(ld, t, c) load_lds16(A + aoff[ld] + (t) * 64, \
                                &A_lds[(c) * 16384 + ((ld) * 512 + tid) * 8])
#define SB(ld, t, c) load_lds16(W + boff[ld] + (t) * 64, \
                                &B_lds[(c) * 16384 + ((ld) * 512 + tid) * 8])
#define WAIT_LGKM0 asm volatile("s_waitcnt lgkmcnt(0)" ::: "memory")
#define WAIT_VM6   asm volatile("s_waitcnt vmcnt(6)"  ::: "memory")
#define WAIT_VM0   asm volatile("s_waitcnt vmcnt(0)"  ::: "memory")

#define READ_AF(p) \
    af[0][0] = *(const bf16x8*)&A_lds[cb + abase + ((p) * 2 + 0) * 1024 + ck0]; \
    af[0][1] = *(const bf16x8*)&A_lds[cb + abase + ((p) * 2 + 0) * 1024 + ck1]; \
    af[1][0] = *(const bf16x8*)&A_lds[cb + abase + ((p) * 2 + 1) * 1024 + ck0]; \
    af[1][1] = *(const bf16x8*)&A_lds[cb + abase + ((p) * 2 + 1) * 1024 + ck1];

#define MFMA_PHASE(p) \
    __builtin_amdgcn_s_setprio(1); \
    if (swap) { \
        _Pragma("unroll") \
        for (int mfi = 0; mfi < 2; ++mfi) \
            _Pragma("unroll") \
            for (int nf = 0; nf < 4; ++nf) { \
                acc[(p) * 2 + mfi][nf] = __builtin_amdgcn_mfma_f32_16x16x32_bf16( \
                    bfrag[nf][0], af[mfi][0], acc[(p) * 2 + mfi][nf], 0, 0, 0); \
                acc[(p) * 2 + mfi][nf] = __builtin_amdgcn_mfma_f32_16x16x32_bf16( \
                    bfrag[nf][1], af[mfi][1], acc[(p) * 2 + mfi][nf], 0, 0, 0); \
            } \
    } else { \
        _Pragma("unroll") \
        for (int mfi = 0; mfi < 2; ++mfi) \
            _Pragma("unroll") \
            for (int nf = 0; nf < 4; ++nf) { \
                acc[(p) * 2 + mfi][nf] = __builtin_amdgcn_mfma_f32_16x16x32_bf16( \
                    af[mfi][0], bfrag[nf][0], acc[(p) * 2 + mfi][nf], 0, 0, 0); \
                acc[(p) * 2 + mfi][nf] = __builtin_amdgcn_mfma_f32_16x16x32_bf16( \
                    af[mfi][1], bfrag[nf][1], acc[(p) * 2 + mfi][nf], 0, 0, 0); \
            } \
    } \
    __builtin_amdgcn_s_setprio(0);

    // ---- prologue: tile0 complete (8), tile1 B+A-lo (6) ----
    SB(0, 0, 0); SB(1, 0, 0); SB(2, 0, 0); SB(3, 0, 0);
    SA(0, 0, 0); SA(1, 0, 0); SA(2, 0, 0); SA(3, 0, 0);
    SB(0, 1, 1); SB(1, 1, 1); SB(2, 1, 1); SB(3, 1, 1);
    SA(0, 1, 1); SA(2, 1, 1);               // ld0,ld2 = rows 0-63 & 128-191
    WAIT_VM6;                               // tile0 done; tile1's 6 in flight
    __builtin_amdgcn_s_barrier();

    for (int t = 0; t < 16; ++t) {
        const int c = t & 1, o = c ^ 1;
        const int cb = c * 16384;
        bf16x8 bfrag[4][2];
        bf16x8 af[2][2];

        // ---- phase 0: B frags + A quadrant 0 ----
        #pragma unroll
        for (int nf = 0; nf < 4; ++nf) {
            bfrag[nf][0] = *(const bf16x8*)&B_lds[cb + bbase + nf * 1024 + ck0];
            bfrag[nf][1] = *(const bf16x8*)&B_lds[cb + bbase + nf * 1024 + ck1];
        }
        READ_AF(0);
        if (t < 15) { SA(1, t + 1, o); SA(3, t + 1, o); }
        __builtin_amdgcn_s_barrier();
        WAIT_LGKM0; __builtin_amdgcn_sched_barrier(0);
        MFMA_PHASE(0);
        __builtin_amdgcn_s_barrier();       // T0: B(cur) now dead

        // ---- phase 1 ----
        READ_AF(1);
        if (t < 14) { SB(0, t + 2, c); SB(1, t + 2, c);
                      SB(2, t + 2, c); SB(3, t + 2, c); }
        __builtin_amdgcn_s_barrier();
        WAIT_LGKM0; __builtin_amdgcn_sched_barrier(0);
        MFMA_PHASE(1);
        __builtin_amdgcn_s_barrier();       // T1: A-lo(cur) now dead

        // ---- phase 2 ----
        READ_AF(2);
        if (t < 14) { SA(0, t + 2, c); SA(2, t + 2, c); }
        __builtin_amdgcn_s_barrier();
        WAIT_LGKM0; __builtin_amdgcn_sched_barrier(0);
        MFMA_PHASE(2);
        // no trailing barrier: nothing stages into regions read in p2/p3
        // until after the boundary barrier.

        // ---- phase 3 ----
        READ_AF(3);
        __builtin_amdgcn_s_barrier();
        WAIT_LGKM0; __builtin_amdgcn_sched_barrier(0);
        MFMA_PHASE(3);

        // ---- tile boundary: next buffer complete, 6 loads stay in flight ----
        if (t < 14)       { WAIT_VM6; __builtin_amdgcn_s_barrier(); }
        else if (t == 14) { WAIT_VM0; __builtin_amdgcn_s_barrier(); }
    }

    // ---- epilogue ----
    const int rb = quad * 4;
    if (MODE == 1) {
        // out proj: D[col = token m][regs = feature] -> float4 stores
        #pragma unroll
        for (int mf = 0; mf < 8; ++mf) {
            const int m = m0 + wr * 128 + mf * 16 + fr;
            if (m < NROWS) {
                #pragma unroll
                for (int nf = 0; nf < 4; ++nf) {
                    const int o_ = n0 + wc * 64 + nf * 16 + rb;
                    float4 pk;
                    pk.x = acc[mf][nf][0];
                    pk.y = acc[mf][nf][1];
                    pk.z = acc[mf][nf][2];
                    pk.w = acc[mf][nf][3];
                    *(float4*)(Out + (long)m * DIMC + o_) = pk;
                }
            }
        }
    } else if (swap) {
        // Q/K: D[col = token m][regs = feature]; wave-col (wc) = one head.
        // Fused RMSNorm + RoPE. Table staged to LDS with the norm weight
        // folded in: U[r][f] = (w[f]*cos[n][f], w[f^32]*sin[n][f]).
        const int part   = n0 >> 10;                 // 0 = Q, 1 = K
        const int hgbase = ((n0 & 1023) + wc * 64) >> 6;
        const float* wtab = (part == 0) ? nqw : nkw;

        float* T = (float*)SMEM;
        __syncthreads();                     // all waves done with GEMM LDS
        for (int e = tid; e < 256 * 16; e += 512) {
            const int row = e >> 4, seg = e & 15;
            const int mm  = m0 + row;
            const int bb2 = mm / NTOK;
            const int n2  = mm - bb2 * NTOK;  // <= 1031 even for dead rows
            const float4 c4 = *(const float4*)(cosb + n2 * 64 + seg * 4);
            const float4 s4 = *(const float4*)(sinb + n2 * 64 + seg * 4);
            const float4 wf = *(const float4*)(wtab + seg * 4);
            const float4 wp = *(const float4*)(wtab + ((seg ^ 8) * 4));
            float* dst = T + row * 132 + seg * 8;
            ((float2*)dst)[0] = make_float2(c4.x * wf.x, s4.x * wp.x);
            ((float2*)dst)[1] = make_float2(c4.y * wf.y, s4.y * wp.y);
            ((float2*)dst)[2] = make_float2(c4.z * wf.z, s4.z * wp.z);
            ((float2*)dst)[3] = make_float2(c4.w * wf.w, s4.w * wp.w);
        }
        __syncthreads();

        // Per-mf macro: LITERAL mf -> all acc indices compile-time (rule #20).
#define QK_NF(MF, NF, PN, SGN) { \
        const float4 q0 = *(const float4*)(trow + ((NF) * 16 + rb) * 2); \
        const float4 q1 = *(const float4*)(trow + ((NF) * 16 + rb) * 2 + 4); \
        ushort4 pk; \
        pk.x = f2bf(rms * (acc[MF][NF][0] * q0.x + (SGN) * acc[MF][PN][0] * q0.y)); \
        pk.y = f2bf(rms * (acc[MF][NF][1] * q0.z + (SGN) * acc[MF][PN][1] * q0.w)); \
        pk.z = f2bf(rms * (acc[MF][NF][2] * q1.x + (SGN) * acc[MF][PN][2] * q1.y)); \
        pk.w = f2bf(rms * (acc[MF][NF][3] * q1.z + (SGN) * acc[MF][PN][3] * q1.w)); \
        *(ushort4*)(outb + (NF) * 16) = pk; }

#define QK_MF(MF) { \
        const int rr = wr * 128 + (MF) * 16 + fr; \
        const int m  = m0 + rr; \
        if (m < NROWS) { \
            const int bb = m / NTOK, n = m - bb * NTOK; \
            float ss = 0.f; \
            _Pragma("unroll") \
            for (int nf = 0; nf < 4; ++nf) { \
                ss += acc[MF][nf][0] * acc[MF][nf][0]; \
                ss += acc[MF][nf][1] * acc[MF][nf][1]; \
                ss += acc[MF][nf][2] * acc[MF][nf][2]; \
                ss += acc[MF][nf][3] * acc[MF][nf][3]; \
            } \
            ss += __shfl_xor(ss, 16, 64); \
            ss += __shfl_xor(ss, 32, 64); \
            const float rms = rsqrtf(ss * (1.0f / 64.0f) + 1e-6f); \
            const float* trow = T + rr * 132; \
            ushort_t* outb = QKV + (long)part * QKV_ELEMS + \
                ((long)(bb * 16 + hgbase) * NTOK + n) * 64 + rb; \
            QK_NF(MF, 0, 2, -1.f) \
            QK_NF(MF, 1, 3, -1.f) \
            QK_NF(MF, 2, 0,  1.f) \
            QK_NF(MF, 3, 1,  1.f) \
        } }

        QK_MF(0) QK_MF(1) QK_MF(2) QK_MF(3)
        QK_MF(4) QK_MF(5) QK_MF(6) QK_MF(7)
#undef QK_MF
#undef QK_NF
    } else {
        // V: D[col = feature][regs = token] -> Vt[bh][d][n] (dim-major)
        const int hg = ((n0 & 1023) + wc * 64) >> 6;
        #pragma unroll
        for (int nf = 0; nf < 4; ++nf) {
            const int d = nf * 16 + fr;
            #pragma unroll
            for (int mf = 0; mf < 8; ++mf) {
                const int mb = m0 + wr * 128 + mf * 16 + rb;
                if (mb < NROWS) {
                    const int bb = mb / NTOK, n = mb - bb * NTOK;
                    ushort4 pk;
                    pk.x = f2bf(acc[mf][nf][0]);
                    pk.y = f2bf(acc[mf][nf][1]);
                    pk.z = f2bf(acc[mf][nf][2]);
                    pk.w = f2bf(acc[mf][nf][3]);
                    *(ushort4*)(QKV + 2L * QKV_ELEMS +
                        ((long)((bb * 16 + hg) * 64 + d)) * NTOK + n) = pk;
                }
            }
        }
    }
#undef SA
#undef SB
#undef WAIT_LGKM0
#undef WAIT_VM6
#undef WAIT_VM0
#undef READ_AF
#undef MFMA_PHASE
}

// ---------------------------------------------------------------------------
// Merged attention. ROUND-6: K LDS staging DELETED. Each wave's QK^T
// B-fragments come only from its own 64 K-slots (no cross-wave sharing), and
// K/V per (b,h) is 264KB L2-resident (same-bh blocks sit at stride 128 = 0
// mod 8 -> same XCD). Direct global fragment loads, identical values
// (Common-mistake #7: don't LDS-stage L2-fit data). LDS is now P-only
// (32x280 ushort = 17.9KB, was 36.9KB -> occupancy up); barriers: patch
// path 4->1, special path 4->2 per chunk.
// ---------------------------------------------------------------------------
__global__ __launch_bounds__(256) void attn_kernel(
    const ushort_t* __restrict__ Qb, const ushort_t* __restrict__ Kb,
    const ushort_t* __restrict__ Vt, ushort_t* __restrict__ AO)
{
    __shared__ __align__(16) ushort_t KP_s[32 * 280];

    const int tid = threadIdx.x;
    const int wave = tid >> 6, lane = tid & 63;
    const int m_ = lane & 15, quad = lane >> 4;
    const int nb = wave * 64;
    const int d0 = wave * 16;

    bf16x8 ones;
    #pragma unroll
    for (int e = 0; e < 8; ++e) ones[e] = (__bf16)1.0f;

    if (blockIdx.x >= 128) {
        // ================= PATCH =================
        const int blk = blockIdx.x - 128;
        const int bh = blk & 127, qr = blk >> 7;
        const int b = bh >> 4, h = bh & 15;

        int r0 = qr - 3; if (r0 < 0) r0 = 0;
        int r1 = qr + 3; if (r1 > 31) r1 = 31;
        const int limit = 8 + (r1 - r0 + 1) * 32;

        const ushort_t* Qg  = Qb + ((long)bh * NTOK + 8 + qr * 32) * 64;
        const ushort_t* Kg  = Kb + (long)bh * NTOK * 64;
        const ushort_t* Vtg = Vt + (long)bh * 64 * NTOK;

        bf16x8 af[2][2];
        #pragma unroll
        for (int mt = 0; mt < 2; ++mt)
            #pragma unroll
            for (int ks = 0; ks < 2; ++ks)
                af[mt][ks] = *(const bf16x8*)(Qg + (mt * 16 + m_) * 64 + ks * 32 + quad * 8);

        bf16x8 bv[8];
        #pragma unroll
        for (int ks = 0; ks < 8; ++ks) {
            const int slot0 = ks * 32 + quad * 8;
            int tok0;
            if (slot0 >= limit) tok0 = 0;
            else if (slot0 < 8) tok0 = slot0;
            else tok0 = 8 + r0 * 32 + (slot0 - 8);
            bv[ks] = *(const bf16x8*)(Vtg + (long)(d0 + m_) * NTOK + tok0);
        }

        // K fragments direct from global (L2-resident), same values the
        // staged path produced: tok = slot + (slot>=8 ? r0*32 : 0).
        bf16x8 bfr[4][2];
        #pragma unroll
        for (int nt = 0; nt < 4; ++nt) {
            const int slot = nb + nt * 16 + m_;
            int tok = (slot < 8) ? slot : (slot + r0 * 32);
            if (slot >= limit) tok = 0;       // clamp in-bounds; masked later
            #pragma unroll
            for (int ks = 0; ks < 2; ++ks)
                bfr[nt][ks] = *(const bf16x8*)(Kg + (long)tok * 64 + ks * 32 + quad * 8);
        }

        f32x4 sacc[2][4] = {};
        #pragma unroll
        for (int mt = 0; mt < 2; ++mt)
            #pragma unroll
            for (int nt = 0; nt < 4; ++nt) {
                sacc[mt][nt] = __builtin_amdgcn_mfma_f32_16x16x32_bf16(
                    af[mt][0], bfr[nt][0], sacc[mt][nt], 0, 0, 0);
                sacc[mt][nt] = __builtin_amdgcn_mfma_f32_16x16x32_bf16(
                    af[mt][1], bfr[nt][1], sacc[mt][nt], 0, 0, 0);
            }

        #pragma unroll
        for (int mt = 0; mt < 2; ++mt)
            #pragma unroll
            for (int nt = 0; nt < 4; ++nt) {
                const int slot = nb + nt * 16 + m_;
                const int kc = (slot - 8) & 31;
                #pragma unroll
                for (int reg = 0; reg < 4; ++reg) {
                    const int qm = mt * 16 + quad * 4 + reg;
                    const bool val = (slot < 8) ||
                        ((slot < limit) && ((unsigned)(kc - qm + 3) <= 6u));
                    const float p = val ? __expf(sacc[mt][nt][reg] * 0.125f) : 0.f;
                    KP_s[qm * 280 + slot] = f2bf(p);
                }
            }
        __syncthreads();                      // only barrier: P visible

        f32x4 oacc[2] = {}, lacc[2] = {};
        #pragma unroll
        for (int ks = 0; ks < 8; ++ks) {
            #pragma unroll
            for (int mt = 0; mt < 2; ++mt) {
                const bf16x8 ap = *(const bf16x8*)&KP_s[(mt * 16 + m_) * 280 + ks * 32 + quad * 8];
                oacc[mt] = __builtin_amdgcn_mfma_f32_16x16x32_bf16(ap, bv[ks], oacc[mt], 0, 0, 0);
                lacc[mt] = __builtin_amdgcn_mfma_f32_16x16x32_bf16(ap, ones,   lacc[mt], 0, 0, 0);
            }
        }
        #pragma unroll
        for (int mt = 0; mt < 2; ++mt)
            #pragma unroll
            for (int reg = 0; reg < 4; ++reg) {
                const int qm = mt * 16 + quad * 4 + reg;
                const int tok = 8 + qr * 32 + qm;
                AO[((long)(b * NTOK + tok)) * DIMC + h * 64 + d0 + m_] =
                    f2bf(oacc[mt][reg] / lacc[mt][reg]);
            }
    } else {
        // ================= SPECIAL =================
        const int bh = blockIdx.x;
        const int b = bh >> 4, h = bh & 15;
        const ushort_t* Kg  = Kb + (long)bh * NTOK * 64;
        const ushort_t* Vtg = Vt + (long)bh * 64 * NTOK;

        bf16x8 afs[2];
        if (m_ < 8) {
            #pragma unroll
            for (int ks = 0; ks < 2; ++ks)
                afs[ks] = *(const bf16x8*)(Qb + ((long)bh * NTOK + m_) * 64 + ks * 32 + quad * 8);
        } else {
            #pragma unroll
            for (int ks = 0; ks < 2; ++ks)
                #pragma unroll
                for (int e = 0; e < 8; ++e) afs[ks][e] = (__bf16)0.f;
        }

        f32x4 oacc = {}, lacc = {};
        for (int ch = 0; ch < 5; ++ch) {
            const int tok0 = ch * 256;
            const int limit = (NTOK - tok0 < 256) ? (NTOK - tok0) : 256;

            bf16x8 bv[8];
            #pragma unroll
            for (int ks = 0; ks < 8; ++ks) {
                const int slot0 = ks * 32 + quad * 8;
                const int tok = tok0 + ((slot0 < limit) ? slot0 : 0);
                bv[ks] = *(const bf16x8*)(Vtg + (long)(d0 + m_) * NTOK + tok);
            }

            // K fragments direct from global
            bf16x8 bfr[4][2];
            #pragma unroll
            for (int nt = 0; nt < 4; ++nt) {
                const int slot = nb + nt * 16 + m_;
                const int tok = tok0 + ((slot < limit) ? slot : 0);
                #pragma unroll
                for (int ks = 0; ks < 2; ++ks)
                    bfr[nt][ks] = *(const bf16x8*)(Kg + (long)tok * 64 + ks * 32 + quad * 8);
            }
            f32x4 sacc[4] = {};
            #pragma unroll
            for (int nt = 0; nt < 4; ++nt) {
                sacc[nt] = __builtin_amdgcn_mfma_f32_16x16x32_bf16(afs[0], bfr[nt][0], sacc[nt], 0, 0, 0);
                sacc[nt] = __builtin_amdgcn_mfma_f32_16x16x32_bf16(afs[1], bfr[nt][1], sacc[nt], 0, 0, 0);
            }

            __syncthreads();                  // previous chunk's PV reads done
            #pragma unroll
            for (int nt = 0; nt < 4; ++nt) {
                const int slot = nb + nt * 16 + m_;
                const bool val = (slot < limit);
                #pragma unroll
                for (int reg = 0; reg < 4; ++reg) {
                    const int qm = quad * 4 + reg;
                    const float p = val ? __expf(sacc[nt][reg] * 0.125f) : 0.f;
                    KP_s[qm * 280 + slot] = f2bf(p);
                }
            }
            __syncthreads();                  // P visible

            #pragma unroll
            for (int ks = 0; ks < 8; ++ks) {
                const bf16x8 ap = *(const bf16x8*)&KP_s[m_ * 280 + ks * 32 + quad * 8];
                oacc = __builtin_amdgcn_mfma_f32_16x16x32_bf16(ap, bv[ks], oacc, 0, 0, 0);
                lacc = __builtin_amdgcn_mfma_f32_16x16x32_bf16(ap, ones,   lacc, 0, 0, 0);
            }
        }

        #pragma unroll
        for (int reg = 0; reg < 4; ++reg) {
            const int qm = quad * 4 + reg;
            if (qm < 8) {
                AO[((long)(b * NTOK + qm)) * DIMC + h * 64 + d0 + m_] =
                    f2bf(oacc[reg] / lacc[reg]);
            }
        }
    }
}

extern "C" void kernel_launch(void* const* d_in, const int* in_sizes, int n_in,
                              void* d_out, int out_size, void* d_ws, size_t ws_size,
                              hipStream_t stream) {
    const float* X    = (const float*)d_in[0];
    const float* fc   = (const float*)d_in[1];
    const float* fs   = (const float*)d_in[2];
    const float* qkvw = (const float*)d_in[3];
    const float* outw = (const float*)d_in[4];
    const float* nqw  = (const float*)d_in[5];
    const float* nkw  = (const float*)d_in[6];

    ushort_t* Qb  = (ushort_t*)d_ws;
    ushort_t* Kb  = Qb + QKV_ELEMS;
    ushort_t* Vt  = Kb + QKV_ELEMS;
    ushort_t* AO  = Vt + QKV_ELEMS;
    ushort_t* Xb  = AO + QKV_ELEMS;
    ushort_t* Wqb = Xb + XE;
    ushort_t* Wob = Wqb + QWE;
    float* Out = (float*)d_out;

    cvt_kernel<<<6176, 256, 0, stream>>>(X, qkvw, outw, Xb, Wqb, Wob);
    gemm256_kernel<0><<<dim3(12, 33), 512, 0, stream>>>(Xb, Wqb, Qb, nullptr,
                                                        fc, fs, nqw, nkw);
    attn_kernel<<<4224, 256, 0, stream>>>(Qb, Kb, Vt, AO);
    gemm256_kernel<1><<<dim3(4, 33), 512, 0, stream>>>(AO, Wob, nullptr, Out,
                                                       fc, fs, nqw, nkw);
}